// Round 1
// 510.273 us; speedup vs baseline: 1.0121x; 1.0121x over previous
//
#include <hip/hip_runtime.h>
#include <hip/hip_bf16.h>

typedef __attribute__((ext_vector_type(8))) short bf16x8;
typedef __attribute__((ext_vector_type(4))) float f32x4;

#define BSHIFT 8          // cols per bucket = 256
#define BW 256
#define NSTR 8            // stripes (XCDs)
#define BCAP 768          // records per (bucket,stripe) stream; mean ~511
#define LCAP 24           // LDS records per bucket per round
#define KEDGE 16          // edges per thread per round (4096/block-round)

__device__ __forceinline__ float lk(float v) { return v > 0.f ? v : 0.01f * v; }

__device__ __forceinline__ short f2b(float v) {
  union { __hip_bfloat16 h; short s; } u;
  u.h = __float2bfloat16(v);
  return u.s;
}
__device__ __forceinline__ float loadF(const void* p, size_t i, int f32) {
  return f32 ? ((const float*)p)[i]
             : __bfloat162float(((const __hip_bfloat16*)p)[i]);
}
__device__ __forceinline__ void storeF(void* p, size_t i, int f32, float v) {
  if (f32) ((float*)p)[i] = v;
  else     ((__hip_bfloat16*)p)[i] = __float2bfloat16(v);
}
__device__ __forceinline__ int loadI(const int* p, size_t base, size_t e, int i64) {
  return i64 ? p[2 * (base + e)] : p[base + e];
}

// ---- dtype detection (device-side, graph-safe) ------------------------------
__global__ void detect_kernel(const unsigned short* __restrict__ x,
                              const int* __restrict__ ei, int* __restrict__ flags) {
  int t = threadIdx.x;
  unsigned short u = x[t];
  int ex = (u >> 7) & 0xFF;
  if (ex >= 0xC0) atomicOr(&flags[0], 1);          // fp32 viewed as bf16 -> wild exps
  if (t < 128 && ei[2 * t + 1] != 0) atomicOr(&flags[1], 1);  // nonzero -> int32
}

// ---- pack W [K,N] row-major -> MFMA B-fragment layout (bf16) ----------------
__global__ __launch_bounds__(64) void pack_w_kernel(const void* __restrict__ W,
                                                    __hip_bfloat16* __restrict__ P,
                                                    int N, const int* __restrict__ flags) {
  int f32 = flags[0] != 0;
  int ks = blockIdx.x, ct = blockIdx.y, KS = gridDim.x;
  int lane = threadIdx.x;
  int g = lane >> 4, m = lane & 15;
  size_t base = ((size_t)(ct * KS + ks) * 64 + (size_t)lane) * 8;
#pragma unroll
  for (int j = 0; j < 8; ++j)
    P[base + j] = __float2bfloat16(
        loadF(W, (size_t)(ks * 32 + g * 8 + j) * N + (size_t)(ct * 16 + m), f32));
}

// ---- GEMM core: fully unrolled K-loop, MT row-tiles reuse B fragments -------
template <int CT, int KS, int MT, int AF32>
__device__ __forceinline__ void gemm_core(const void* __restrict__ A,
                                          const __hip_bfloat16* __restrict__ bbase,
                                          const int (&rowA)[MT], int g,
                                          f32x4 (&accs)[MT][CT]) {
  constexpr int K = KS * 32;
#pragma unroll
  for (int ks = 0; ks < KS; ++ks) {
    bf16x8 a[MT];
#pragma unroll
    for (int t = 0; t < MT; ++t) {
      if constexpr (AF32) {
        const float* ap = (const float*)A + (size_t)rowA[t] * K + ks * 32 + g * 8;
        float4 p0 = *(const float4*)ap;
        float4 p1 = *(const float4*)(ap + 4);
        a[t][0] = f2b(p0.x); a[t][1] = f2b(p0.y); a[t][2] = f2b(p0.z); a[t][3] = f2b(p0.w);
        a[t][4] = f2b(p1.x); a[t][5] = f2b(p1.y); a[t][6] = f2b(p1.z); a[t][7] = f2b(p1.w);
      } else {
        a[t] = *(const bf16x8*)((const __hip_bfloat16*)A +
                                (size_t)rowA[t] * K + ks * 32 + g * 8);
      }
    }
    const __hip_bfloat16* bb = bbase + (size_t)ks * 64 * 8;
#pragma unroll
    for (int c = 0; c < CT; ++c) {
      bf16x8 b = *(const bf16x8*)(bb + (size_t)c * KS * 64 * 8);
#pragma unroll
      for (int t = 0; t < MT; ++t)
        accs[t][c] = __builtin_amdgcn_mfma_f32_16x16x32_bf16(a[t], b, accs[t][c], 0, 0, 0);
    }
  }
}

// ---- GEMM: Out[M,N] = act(A @ Bp + bias); optional y = dinv[row]*val --------
template <int CT, int KS, int MT>
__global__ __launch_bounds__(256) void gemm_kernel(const void* __restrict__ A,
                                                   const __hip_bfloat16* __restrict__ Bp,
                                                   const void* __restrict__ bias,
                                                   void* __restrict__ Out, int out_bf16,
                                                   __hip_bfloat16* __restrict__ Yout,
                                                   const float* __restrict__ dinv,
                                                   int M, int N, int act,
                                                   int a_use_flag,
                                                   const int* __restrict__ flags) {
  int f32 = flags[0] != 0;
  int af32 = a_use_flag ? f32 : 0;     // intermediates are stored bf16
  int lane = threadIdx.x & 63;
  int wid = blockIdx.x * 4 + (threadIdx.x >> 6);
  int WPR = N / (16 * CT);
  int nsb = (M + 16 * MT - 1) / (16 * MT);
  int rowsb = wid / WPR;
  int colpart = wid - rowsb * WPR;
  if (rowsb >= nsb) return;
  int m = lane & 15, g = lane >> 4;
  int row0 = rowsb * (16 * MT);
  int rowA[MT];
#pragma unroll
  for (int t = 0; t < MT; ++t) {
    int r = row0 + t * 16 + m;
    rowA[t] = r < M ? r : M - 1;
  }
  const __hip_bfloat16* bbase = Bp + ((size_t)(colpart * CT) * KS * 64 + (size_t)lane) * 8;
  f32x4 accs[MT][CT];
#pragma unroll
  for (int t = 0; t < MT; ++t)
#pragma unroll
    for (int c = 0; c < CT; ++c) accs[t][c] = (f32x4){0, 0, 0, 0};

  if (af32) gemm_core<CT, KS, MT, 1>(A, bbase, rowA, g, accs);
  else      gemm_core<CT, KS, MT, 0>(A, bbase, rowA, g, accs);

  // epilogue
  float bv[CT];
#pragma unroll
  for (int c = 0; c < CT; ++c)
    bv[c] = bias ? loadF(bias, (size_t)((colpart * CT + c) * 16 + m), f32) : 0.f;
#pragma unroll
  for (int t = 0; t < MT; ++t) {
#pragma unroll
    for (int r = 0; r < 4; ++r) {
      int ro = row0 + t * 16 + g * 4 + r;
      if (ro < M) {
        float di = Yout ? dinv[ro] : 0.f;
#pragma unroll
        for (int c = 0; c < CT; ++c) {
          int col = (colpart * CT + c) * 16 + m;
          float v = accs[t][c][r] + bv[c];
          if (act) v = lk(v);
          if (out_bf16) ((__hip_bfloat16*)Out)[(size_t)ro * N + col] = __float2bfloat16(v);
          else          ((float*)Out)[(size_t)ro * N + col] = v;
          if (Yout) Yout[(size_t)ro * N + col] = __float2bfloat16(v * di);
        }
      }
    }
  }
}

// ---- CSR build pass A: LDS-staged binning, batched stream flush -------------
// LDS: bcnt[NB] | gbase[NB] | bins[NB*LCAP] (int2)
__global__ __launch_bounds__(256) void bin_kernel(const int* __restrict__ ei,
                                                  int* __restrict__ cur,
                                                  int2* __restrict__ rec,
                                                  int E, int NB,
                                                  const int* __restrict__ flags) {
  extern __shared__ int lds[];
  int* bcnt = lds;
  int* gbase = lds + NB;
  int2* bins = (int2*)(lds + 2 * NB);
  int i64 = flags[1] == 0;
  // real XCD id (hwreg 20); any value is correctness-safe after &7
  int stripe = __builtin_amdgcn_s_getreg(63508) & (NSTR - 1);
  int t = threadIdx.x;
  const int perRound = 256 * KEDGE;
  for (int base = blockIdx.x * perRound; base < E; base += gridDim.x * perRound) {
    for (int b = t; b < NB; b += 256) bcnt[b] = 0;
    __syncthreads();
    // bin into LDS
#pragma unroll 1
    for (int k = 0; k < KEDGE; ++k) {
      int i = base + k * 256 + t;
      if (i < E) {
        int r = loadI(ei, 0, (size_t)i, i64);
        int c = loadI(ei, (size_t)E, (size_t)i, i64);
        int b = c >> BSHIFT;
        int pos = atomicAdd(&bcnt[b], 1);
        if (pos < LCAP) {
          bins[b * LCAP + pos] = make_int2(r, c);
        } else {                                   // rare overflow: direct append
          int bs = b * NSTR + stripe;
          int slot = atomicAdd(&cur[bs], 1);
          if (slot < BCAP) rec[(size_t)bs * BCAP + slot] = make_int2(r, c);
        }
      }
    }
    __syncthreads();
    // reserve stream ranges (parallel atomics, no serialized chain)
    for (int b = t; b < NB; b += 256) {
      int n = min(bcnt[b], LCAP);
      if (n > 0) gbase[b] = atomicAdd(&cur[b * NSTR + stripe], n);
    }
    __syncthreads();
    // contiguous copy LDS -> stream
    int lane = t & 63, w = t >> 6;
    for (int b = w; b < NB; b += 4) {
      int n = min(bcnt[b], LCAP);
      if (n == 0) continue;
      int gb = gbase[b];
      size_t sb = (size_t)(b * NSTR + stripe) * BCAP;
      if (lane < n && gb + lane < BCAP)
        rec[sb + gb + lane] = bins[b * LCAP + lane];
    }
    __syncthreads();
  }
}

// exclusive prefix over bucket totals (single block; NB <= 512)
__global__ __launch_bounds__(512) void bucket_scan(const int* __restrict__ cur,
                                                   int* __restrict__ bbase, int NB) {
  __shared__ int lds[512];
  int t = threadIdx.x;
  int tot = 0;
  if (t < NB)
#pragma unroll
    for (int s = 0; s < NSTR; ++s) tot += min(cur[t * NSTR + s], BCAP);
  lds[t] = tot; __syncthreads();
  for (int o = 1; o < 512; o <<= 1) {
    int a = (t >= o) ? lds[t - o] : 0; __syncthreads();
    lds[t] += a; __syncthreads();
  }
  if (t < NB) bbase[t] = lds[t] - tot;
}

// Pass B: one block per bucket. LDS count -> scan -> rowptr/dinv -> place
__global__ __launch_bounds__(256) void place_kernel(const int2* __restrict__ rec,
                                                    const int* __restrict__ cur,
                                                    const int* __restrict__ bbase,
                                                    int* __restrict__ rowptr,
                                                    int* __restrict__ csr,
                                                    float* __restrict__ dinv, int Nn) {
  int b = blockIdx.x;
  int lo = b << BSHIFT;
  int t = threadIdx.x;
  __shared__ int cnt[BW];
  __shared__ int sc[BW];
  __shared__ int cursor[BW];
  cnt[t] = 0;
  __syncthreads();
#pragma unroll 1
  for (int s = 0; s < NSTR; ++s) {
    int n = min(cur[b * NSTR + s], BCAP);
    const int2* rp = rec + (size_t)(b * NSTR + s) * BCAP;
    for (int j = t; j < n; j += 256) atomicAdd(&cnt[rp[j].y - lo], 1);
  }
  __syncthreads();
  int v = cnt[t];
  sc[t] = v; __syncthreads();
  for (int o = 1; o < BW; o <<= 1) {
    int a = (t >= o) ? sc[t - o] : 0; __syncthreads();
    sc[t] += a; __syncthreads();
  }
  int base = bbase[b];
  int col = lo + t;
  if (col < Nn) {
    rowptr[col] = base + sc[t];                 // segment END
    dinv[col] = rsqrtf((float)v + 1.0f);
  }
  cursor[t] = base + sc[t] - v;                 // segment start
  __syncthreads();
#pragma unroll 1
  for (int s = 0; s < NSTR; ++s) {
    int n = min(cur[b * NSTR + s], BCAP);
    const int2* rp = rec + (size_t)(b * NSTR + s) * BCAP;
    for (int j = t; j < n; j += 256) {
      int2 e = rp[j];
      int pos = atomicAdd(&cursor[e.y - lo], 1);
      csr[pos] = e.x;
    }
  }
}

// ---- pull-mode aggregation + self-term + bias + leaky, fused ----------------
__global__ __launch_bounds__(256) void gather_kernel(const __hip_bfloat16* __restrict__ y,
                                                     const float* __restrict__ xw,
                                                     const int* __restrict__ csr,
                                                     const int* __restrict__ rowptr,
                                                     const float* __restrict__ dinv,
                                                     const void* __restrict__ bias,
                                                     void* __restrict__ outp, size_t obase,
                                                     int out_use_flag, int Nn,
                                                     const int* __restrict__ flags) {
  int f32 = flags[0] != 0;
  int of32 = out_use_flag ? f32 : 0;    // intermediate h3 stored bf16
  int lane = threadIdx.x & 63;
  int node = (blockIdx.x * blockDim.x + threadIdx.x) >> 6;
  if (node >= Nn) return;
  int s = (node == 0) ? 0 : rowptr[node - 1];
  int e = rowptr[node];
  float a0 = 0, a1 = 0, a2 = 0, a3 = 0;
  for (int base = s; base < e; base += 64) {
    int cnt = e - base; if (cnt > 64) cnt = 64;
    int rl = (base + lane < e) ? csr[base + lane] : 0;
    int j = 0;
    for (; j + 4 <= cnt; j += 4) {
      int r0 = __shfl(rl, j, 64), r1 = __shfl(rl, j + 1, 64);
      int r2 = __shfl(rl, j + 2, 64), r3 = __shfl(rl, j + 3, 64);
      a0 += __bfloat162float(y[(size_t)r0 * 64 + lane]);
      a1 += __bfloat162float(y[(size_t)r1 * 64 + lane]);
      a2 += __bfloat162float(y[(size_t)r2 * 64 + lane]);
      a3 += __bfloat162float(y[(size_t)r3 * 64 + lane]);
    }
    for (; j < cnt; ++j) {
      int r0 = __shfl(rl, j, 64);
      a0 += __bfloat162float(y[(size_t)r0 * 64 + lane]);
    }
  }
  float acc = (a0 + a1) + (a2 + a3);
  float di = dinv[node];
  float v = di * acc + xw[(size_t)node * 64 + lane] * di * di + loadF(bias, (size_t)lane, f32);
  storeF(outp, obase + (size_t)node * 64 + lane, of32, lk(v));
}

// ---- edge scoring head ------------------------------------------------------
__global__ __launch_bounds__(256) void edge_head_kernel(void* __restrict__ dout,
                                                        const int* __restrict__ eli,
                                                        const void* __restrict__ ea,
                                                        const void* __restrict__ Wp,
                                                        const void* __restrict__ bp,
                                                        int EL, const int* __restrict__ flags) {
  int f32 = flags[0] != 0;
  int i64 = flags[1] == 0;
  int lane = threadIdx.x & 63;
  int wave = (blockIdx.x * blockDim.x + threadIdx.x) >> 6;
  if (wave >= EL) return;
  size_t hbase = (size_t)EL;
  float wp1 = loadF(Wp, (size_t)lane, f32);
  float wp2 = loadF(Wp, (size_t)(64 + lane), f32);
  float wp3 = lane < 8 ? loadF(Wp, (size_t)(128 + lane), f32) : 0.f;
  int s = loadI(eli, 0, (size_t)wave, i64);
  int d = loadI(eli, (size_t)EL, (size_t)wave, i64);
  float acc = loadF(dout, hbase + (size_t)s * 64 + lane, f32) * wp1 +
              loadF(dout, hbase + (size_t)d * 64 + lane, f32) * wp2;
  if (lane < 8) acc += loadF(ea, (size_t)wave * 8 + lane, f32) * wp3;
#pragma unroll
  for (int o = 32; o > 0; o >>= 1) acc += __shfl_down(acc, o, 64);
  if (lane == 0) storeF(dout, (size_t)wave, f32, acc + loadF(bp, 0, f32));
}

extern "C" void kernel_launch(void* const* d_in, const int* in_sizes, int n_in,
                              void* d_out, int out_size, void* d_ws, size_t ws_size,
                              hipStream_t stream) {
  const void* x   = d_in[0];
  const int* ei   = (const int*)d_in[1];
  const int* eli  = (const int*)d_in[2];
  const void* ea  = d_in[3];
  const void* W1  = d_in[4];
  const void* b1  = d_in[5];
  const void* W2  = d_in[6];
  const void* b2  = d_in[7];
  const void* Wg1 = d_in[8];
  const void* bg1 = d_in[9];
  const void* Wg2 = d_in[10];
  const void* bg2 = d_in[11];
  const void* Wp  = d_in[12];
  const void* bp  = d_in[13];

  const int Nn = in_sizes[0] / 256;
  const int E  = in_sizes[1] / 2;
  const int EL = in_sizes[2] / 2;
  const int NB = (Nn + BW - 1) >> BSHIFT;       // col buckets

  char* ws = (char*)d_ws;
  size_t off = 0;
  auto take = [&](size_t bytes) -> char* {
    char* p = ws + off;
    off = (off + bytes + 255) & ~(size_t)255;
    return p;
  };
  int*   flags  = (int*)take(256);
  int*   cur    = (int*)take((size_t)NB * NSTR * 4);   // contiguous after flags
  int*   bbase  = (int*)take((size_t)NB * 4);
  int*   rowptr = (int*)take((size_t)Nn * 4);
  float* dinv   = (float*)take((size_t)Nn * 4);
  int*   csr    = (int*)take((size_t)E * 4);
  int2*  rec    = (int2*)take((size_t)NB * NSTR * BCAP * 8);
  __hip_bfloat16* pW1 = (__hip_bfloat16*)take(256 * 128 * 2);
  __hip_bfloat16* pW2 = (__hip_bfloat16*)take(128 * 64 * 2);
  __hip_bfloat16* pG1 = (__hip_bfloat16*)take(64 * 64 * 2);
  __hip_bfloat16* pG2 = (__hip_bfloat16*)take(64 * 64 * 2);
  char* regionA = take((size_t)Nn * 128 * 4);   // h1(bf16) | later (xw fp32, y bf16)
  char* regionB = take((size_t)Nn * 64 * 4);    // h2(bf16) | later h3(bf16)
  __hip_bfloat16* h1 = (__hip_bfloat16*)regionA;
  float* xw  = (float*)regionA;
  __hip_bfloat16* y = (__hip_bfloat16*)(regionA + (size_t)Nn * 64 * 4);
  __hip_bfloat16* h2 = (__hip_bfloat16*)regionB;
  __hip_bfloat16* h3 = (__hip_bfloat16*)regionB;

  // flags + cur are contiguous -> one memset covers both
  hipMemsetAsync(flags, 0, 256 + (((size_t)NB * NSTR * 4 + 255) & ~(size_t)255), stream);
  detect_kernel<<<1, 256, 0, stream>>>((const unsigned short*)x, ei, flags);

  dim3 b64(64);
  pack_w_kernel<<<dim3(8, 8), b64, 0, stream>>>(W1, pW1, 128, flags);
  pack_w_kernel<<<dim3(4, 4), b64, 0, stream>>>(W2, pW2, 64, flags);
  pack_w_kernel<<<dim3(2, 4), b64, 0, stream>>>(Wg1, pG1, 64, flags);
  pack_w_kernel<<<dim3(2, 4), b64, 0, stream>>>(Wg2, pG2, 64, flags);

  // CSR build: LDS-staged binning -> scan -> place
  const int ldsbytes = NB * (8 + LCAP * 8);     // bcnt + gbase + bins
  const int nbin = (E + 256 * KEDGE - 1) / (256 * KEDGE);
  bin_kernel<<<nbin, 256, ldsbytes, stream>>>(ei, cur, rec, E, NB, flags);
  bucket_scan<<<1, 512, 0, stream>>>(cur, bbase, NB);
  place_kernel<<<NB, 256, 0, stream>>>(rec, cur, bbase, rowptr, csr, dinv, Nn);

  // MT=2: 32 rows per superblock, 4 waves per block
  const int nsb = (Nn + 31) / 32;
  const int gblocks = (nsb + 3) / 4;
  gemm_kernel<8, 8, 2><<<gblocks, 256, 0, stream>>>(x, pW1, b1, h1, 1, nullptr, nullptr,
                                                    Nn, 128, 1, 1, flags);
  gemm_kernel<4, 4, 2><<<gblocks, 256, 0, stream>>>(h1, pW2, b2, h2, 1, nullptr, nullptr,
                                                    Nn, 64, 1, 0, flags);

  gemm_kernel<4, 2, 2><<<gblocks, 256, 0, stream>>>(h2, pG1, nullptr, xw, 0, y, dinv,
                                                    Nn, 64, 0, 0, flags);
  gather_kernel<<<(Nn + 3) / 4, 256, 0, stream>>>(y, xw, csr, rowptr, dinv, bg1,
                                                  h3, 0, 0, Nn, flags);

  gemm_kernel<4, 2, 2><<<gblocks, 256, 0, stream>>>(h3, pG2, nullptr, xw, 0, y, dinv,
                                                    Nn, 64, 0, 0, flags);
  gather_kernel<<<(Nn + 3) / 4, 256, 0, stream>>>(y, xw, csr, rowptr, dinv, bg2,
                                                  d_out, (size_t)EL, 1, Nn, flags);

  edge_head_kernel<<<(EL + 3) / 4, 256, 0, stream>>>(d_out, eli, ea, Wp, bp, EL, flags);
}

// Round 2
// 477.716 us; speedup vs baseline: 1.0811x; 1.0682x over previous
//
#include <hip/hip_runtime.h>
#include <hip/hip_bf16.h>

typedef __attribute__((ext_vector_type(8))) short bf16x8;
typedef __attribute__((ext_vector_type(4))) float f32x4;

#define BSHIFT 8          // cols per bucket = 256
#define BW 256
#define NSTR 8            // stripes (XCDs)
#define BCAP 768          // records per (bucket,stripe) stream; mean ~511
#define LCAP 24           // LDS records per bucket per round
#define KEDGE 16          // edges per thread per round (4096/block-round)

__device__ __forceinline__ float lk(float v) { return v > 0.f ? v : 0.01f * v; }

__device__ __forceinline__ short f2b(float v) {
  union { __hip_bfloat16 h; short s; } u;
  u.h = __float2bfloat16(v);
  return u.s;
}
__device__ __forceinline__ float loadF(const void* p, size_t i, int f32) {
  return f32 ? ((const float*)p)[i]
             : __bfloat162float(((const __hip_bfloat16*)p)[i]);
}
__device__ __forceinline__ void storeF(void* p, size_t i, int f32, float v) {
  if (f32) ((float*)p)[i] = v;
  else     ((__hip_bfloat16*)p)[i] = __float2bfloat16(v);
}
__device__ __forceinline__ int loadI(const int* p, size_t base, size_t e, int i64) {
  return i64 ? p[2 * (base + e)] : p[base + e];
}

// ---- dtype detection (device-side, graph-safe) ------------------------------
__global__ void detect_kernel(const unsigned short* __restrict__ x,
                              const int* __restrict__ ei, int* __restrict__ flags) {
  int t = threadIdx.x;
  unsigned short u = x[t];
  int ex = (u >> 7) & 0xFF;
  if (ex >= 0xC0) atomicOr(&flags[0], 1);          // fp32 viewed as bf16 -> wild exps
  if (t < 128 && ei[2 * t + 1] != 0) atomicOr(&flags[1], 1);  // nonzero -> int32
}

// ---- pack W [K,N] row-major -> MFMA B-fragment layout (bf16) ----------------
__global__ __launch_bounds__(64) void pack_w_kernel(const void* __restrict__ W,
                                                    __hip_bfloat16* __restrict__ P,
                                                    int N, const int* __restrict__ flags) {
  int f32 = flags[0] != 0;
  int ks = blockIdx.x, ct = blockIdx.y, KS = gridDim.x;
  int lane = threadIdx.x;
  int g = lane >> 4, m = lane & 15;
  size_t base = ((size_t)(ct * KS + ks) * 64 + (size_t)lane) * 8;
#pragma unroll
  for (int j = 0; j < 8; ++j)
    P[base + j] = __float2bfloat16(
        loadF(W, (size_t)(ks * 32 + g * 8 + j) * N + (size_t)(ct * 16 + m), f32));
}

// ---- tiled GEMM with global_load_lds A-staging ------------------------------
// Block = 4 waves, tile = 32 rows x K. Wave w owns col-partition w (CT tiles).
// LDS dest is linear; global SOURCE is pre-swizzled with the same XOR the
// ds reads use (rule 21: both-sides-or-neither).
//   f32  A: frag = 32B = chunk pair (c,c+1), xor = (row&3)<<1 (keeps pairs)
//   bf16 A: frag = 16B = 1 chunk,            xor = (row&7)

template <int ROWB, int F32>
__device__ __forceinline__ void stage_tile(const char* __restrict__ Ab, char* tile,
                                           int row0, int M, int w, int lane) {
  constexpr int CPR = ROWB / 16;     // 16B chunks per row
  constexpr int PERW = 32 * CPR / 4; // chunks per wave (multiple of 64)
#pragma unroll
  for (int i = 0; i < PERW; i += 64) {
    int p = w * PERW + i + lane;
    int r = p / CPR;
    int pc = p - r * CPR;
    int xv = F32 ? ((r & 3) << 1) : (r & 7);
    int gr = row0 + r; if (gr >= M) gr = M - 1;
    const char* src = Ab + (size_t)gr * ROWB + (size_t)(pc ^ xv) * 16;
    char* dst = tile + (size_t)(w * PERW + i) * 16;   // wave-uniform base
    __builtin_amdgcn_global_load_lds(
        (const __attribute__((address_space(1))) void*)src,
        (__attribute__((address_space(3))) void*)dst, 16, 0, 0);
  }
}

template <int KS, int CT, int F32>
__device__ __forceinline__ void tile_core(const char* tile,
                                          const __hip_bfloat16* __restrict__ bbase,
                                          int m, int g, f32x4 (&accs)[2][CT]) {
  constexpr int ROWB = KS * 32 * (F32 ? 4 : 2);
#pragma unroll
  for (int ks = 0; ks < KS; ++ks) {
    bf16x8 a[2];
#pragma unroll
    for (int t = 0; t < 2; ++t) {
      int r = t * 16 + m;
      if constexpr (F32) {
        int c = ks * 8 + g * 2;                 // chunk pair c, c+1
        int xv = (r & 3) << 1;
        float4 q0 = *(const float4*)(tile + (size_t)r * ROWB + (size_t)((c ^ xv) * 16));
        float4 q1 = *(const float4*)(tile + (size_t)r * ROWB + (size_t)(((c + 1) ^ xv) * 16));
        a[t][0] = f2b(q0.x); a[t][1] = f2b(q0.y); a[t][2] = f2b(q0.z); a[t][3] = f2b(q0.w);
        a[t][4] = f2b(q1.x); a[t][5] = f2b(q1.y); a[t][6] = f2b(q1.z); a[t][7] = f2b(q1.w);
      } else {
        int c = ks * 4 + g;                     // single 16B chunk
        int xv = r & 7;
        a[t] = *(const bf16x8*)(tile + (size_t)r * ROWB + (size_t)((c ^ xv) * 16));
      }
    }
    const __hip_bfloat16* bb = bbase + (size_t)ks * 64 * 8;
#pragma unroll
    for (int cc = 0; cc < CT; ++cc) {
      bf16x8 b = *(const bf16x8*)(bb + (size_t)cc * KS * 64 * 8);
#pragma unroll
      for (int t = 0; t < 2; ++t)
        accs[t][cc] = __builtin_amdgcn_mfma_f32_16x16x32_bf16(a[t], b, accs[t][cc], 0, 0, 0);
    }
  }
}

// AMODE: 0 = A always bf16; 1 = A dtype from flags[0] (fp32 or bf16)
template <int KS, int CT, int AMODE>
__global__ __launch_bounds__(256) void gemm_tiled(const void* __restrict__ A,
                                                  const __hip_bfloat16* __restrict__ Bp,
                                                  const void* __restrict__ bias,
                                                  void* __restrict__ Out, int out_bf16,
                                                  __hip_bfloat16* __restrict__ Yout,
                                                  const float* __restrict__ dinv,
                                                  int M, int N, int act,
                                                  const int* __restrict__ flags) {
  constexpr int K = KS * 32;
  constexpr int LDSB = 32 * K * (AMODE ? 4 : 2);
  __shared__ char tile[LDSB];
  int f32 = AMODE ? (flags[0] != 0) : 0;
  int lane = threadIdx.x & 63;
  int w = threadIdx.x >> 6;                     // wave id = col partition
  int m = lane & 15, g = lane >> 4;
  int row0 = blockIdx.x * 32;

  const char* Ab = (const char*)A;
  if (f32) stage_tile<K * 4, 1>(Ab, tile, row0, M, w, lane);
  else     stage_tile<K * 2, 0>(Ab, tile, row0, M, w, lane);
  __syncthreads();

  const __hip_bfloat16* bbase = Bp + ((size_t)(w * CT) * KS * 64 + (size_t)lane) * 8;
  f32x4 accs[2][CT];
#pragma unroll
  for (int t = 0; t < 2; ++t)
#pragma unroll
    for (int cc = 0; cc < CT; ++cc) accs[t][cc] = (f32x4){0, 0, 0, 0};

  if (f32) tile_core<KS, CT, 1>(tile, bbase, m, g, accs);
  else     tile_core<KS, CT, 0>(tile, bbase, m, g, accs);

  // epilogue
  float bv[CT];
#pragma unroll
  for (int cc = 0; cc < CT; ++cc)
    bv[cc] = bias ? loadF(bias, (size_t)((w * CT + cc) * 16 + m), flags[0] != 0) : 0.f;
#pragma unroll
  for (int t = 0; t < 2; ++t) {
#pragma unroll
    for (int r = 0; r < 4; ++r) {
      int ro = row0 + t * 16 + g * 4 + r;
      if (ro < M) {
        float di = Yout ? dinv[ro] : 0.f;
#pragma unroll
        for (int cc = 0; cc < CT; ++cc) {
          int col = (w * CT + cc) * 16 + m;
          float v = accs[t][cc][r] + bv[cc];
          if (act) v = lk(v);
          if (out_bf16) ((__hip_bfloat16*)Out)[(size_t)ro * N + col] = __float2bfloat16(v);
          else          ((float*)Out)[(size_t)ro * N + col] = v;
          if (Yout) Yout[(size_t)ro * N + col] = __float2bfloat16(v * di);
        }
      }
    }
  }
}

// ---- CSR build pass A: LDS-staged binning, batched stream flush -------------
// LDS: bcnt[NB] | gbase[NB] | bins[NB*LCAP] (int2)
__global__ __launch_bounds__(256) void bin_kernel(const int* __restrict__ ei,
                                                  int* __restrict__ cur,
                                                  int2* __restrict__ rec,
                                                  int E, int NB,
                                                  const int* __restrict__ flags) {
  extern __shared__ int lds[];
  int* bcnt = lds;
  int* gbase = lds + NB;
  int2* bins = (int2*)(lds + 2 * NB);
  int i64 = flags[1] == 0;
  // real XCD id (hwreg 20); any value is correctness-safe after &7
  int stripe = __builtin_amdgcn_s_getreg(63508) & (NSTR - 1);
  int t = threadIdx.x;
  const int perRound = 256 * KEDGE;
  for (int base = blockIdx.x * perRound; base < E; base += gridDim.x * perRound) {
    for (int b = t; b < NB; b += 256) bcnt[b] = 0;
    __syncthreads();
    // bin into LDS
#pragma unroll 1
    for (int k = 0; k < KEDGE; ++k) {
      int i = base + k * 256 + t;
      if (i < E) {
        int r = loadI(ei, 0, (size_t)i, i64);
        int c = loadI(ei, (size_t)E, (size_t)i, i64);
        int b = c >> BSHIFT;
        int pos = atomicAdd(&bcnt[b], 1);
        if (pos < LCAP) {
          bins[b * LCAP + pos] = make_int2(r, c);
        } else {                                   // rare overflow: direct append
          int bs = b * NSTR + stripe;
          int slot = atomicAdd(&cur[bs], 1);
          if (slot < BCAP) rec[(size_t)bs * BCAP + slot] = make_int2(r, c);
        }
      }
    }
    __syncthreads();
    // reserve stream ranges (parallel atomics, no serialized chain)
    for (int b = t; b < NB; b += 256) {
      int n = min(bcnt[b], LCAP);
      if (n > 0) gbase[b] = atomicAdd(&cur[b * NSTR + stripe], n);
    }
    __syncthreads();
    // contiguous copy LDS -> stream
    int lane = t & 63, w = t >> 6;
    for (int b = w; b < NB; b += 4) {
      int n = min(bcnt[b], LCAP);
      if (n == 0) continue;
      int gb = gbase[b];
      size_t sb = (size_t)(b * NSTR + stripe) * BCAP;
      if (lane < n && gb + lane < BCAP)
        rec[sb + gb + lane] = bins[b * LCAP + lane];
    }
    __syncthreads();
  }
}

// exclusive prefix over bucket totals (single block; NB <= 512)
__global__ __launch_bounds__(512) void bucket_scan(const int* __restrict__ cur,
                                                   int* __restrict__ bbase, int NB) {
  __shared__ int lds[512];
  int t = threadIdx.x;
  int tot = 0;
  if (t < NB)
#pragma unroll
    for (int s = 0; s < NSTR; ++s) tot += min(cur[t * NSTR + s], BCAP);
  lds[t] = tot; __syncthreads();
  for (int o = 1; o < 512; o <<= 1) {
    int a = (t >= o) ? lds[t - o] : 0; __syncthreads();
    lds[t] += a; __syncthreads();
  }
  if (t < NB) bbase[t] = lds[t] - tot;
}

// Pass B: one block per bucket. LDS count -> scan -> rowptr/dinv -> place
__global__ __launch_bounds__(256) void place_kernel(const int2* __restrict__ rec,
                                                    const int* __restrict__ cur,
                                                    const int* __restrict__ bbase,
                                                    int* __restrict__ rowptr,
                                                    int* __restrict__ csr,
                                                    float* __restrict__ dinv, int Nn) {
  int b = blockIdx.x;
  int lo = b << BSHIFT;
  int t = threadIdx.x;
  __shared__ int cnt[BW];
  __shared__ int sc[BW];
  __shared__ int cursor[BW];
  cnt[t] = 0;
  __syncthreads();
#pragma unroll 1
  for (int s = 0; s < NSTR; ++s) {
    int n = min(cur[b * NSTR + s], BCAP);
    const int2* rp = rec + (size_t)(b * NSTR + s) * BCAP;
    for (int j = t; j < n; j += 256) atomicAdd(&cnt[rp[j].y - lo], 1);
  }
  __syncthreads();
  int v = cnt[t];
  sc[t] = v; __syncthreads();
  for (int o = 1; o < BW; o <<= 1) {
    int a = (t >= o) ? sc[t - o] : 0; __syncthreads();
    sc[t] += a; __syncthreads();
  }
  int base = bbase[b];
  int col = lo + t;
  if (col < Nn) {
    rowptr[col] = base + sc[t];                 // segment END
    dinv[col] = rsqrtf((float)v + 1.0f);
  }
  cursor[t] = base + sc[t] - v;                 // segment start
  __syncthreads();
#pragma unroll 1
  for (int s = 0; s < NSTR; ++s) {
    int n = min(cur[b * NSTR + s], BCAP);
    const int2* rp = rec + (size_t)(b * NSTR + s) * BCAP;
    for (int j = t; j < n; j += 256) {
      int2 e = rp[j];
      int pos = atomicAdd(&cursor[e.y - lo], 1);
      csr[pos] = e.x;
    }
  }
}

// ---- pull-mode aggregation + self-term + bias + leaky, fused ----------------
__global__ __launch_bounds__(256) void gather_kernel(const __hip_bfloat16* __restrict__ y,
                                                     const float* __restrict__ xw,
                                                     const int* __restrict__ csr,
                                                     const int* __restrict__ rowptr,
                                                     const float* __restrict__ dinv,
                                                     const void* __restrict__ bias,
                                                     void* __restrict__ outp, size_t obase,
                                                     int out_use_flag, int Nn,
                                                     const int* __restrict__ flags) {
  int f32 = flags[0] != 0;
  int of32 = out_use_flag ? f32 : 0;    // intermediate h3 stored bf16
  int lane = threadIdx.x & 63;
  int node = (blockIdx.x * blockDim.x + threadIdx.x) >> 6;
  if (node >= Nn) return;
  int s = (node == 0) ? 0 : rowptr[node - 1];
  int e = rowptr[node];
  float a0 = 0, a1 = 0, a2 = 0, a3 = 0;
  for (int base = s; base < e; base += 64) {
    int cnt = e - base; if (cnt > 64) cnt = 64;
    int rl = (base + lane < e) ? csr[base + lane] : 0;
    int j = 0;
    for (; j + 4 <= cnt; j += 4) {
      int r0 = __shfl(rl, j, 64), r1 = __shfl(rl, j + 1, 64);
      int r2 = __shfl(rl, j + 2, 64), r3 = __shfl(rl, j + 3, 64);
      a0 += __bfloat162float(y[(size_t)r0 * 64 + lane]);
      a1 += __bfloat162float(y[(size_t)r1 * 64 + lane]);
      a2 += __bfloat162float(y[(size_t)r2 * 64 + lane]);
      a3 += __bfloat162float(y[(size_t)r3 * 64 + lane]);
    }
    for (; j < cnt; ++j) {
      int r0 = __shfl(rl, j, 64);
      a0 += __bfloat162float(y[(size_t)r0 * 64 + lane]);
    }
  }
  float acc = (a0 + a1) + (a2 + a3);
  float di = dinv[node];
  float v = di * acc + xw[(size_t)node * 64 + lane] * di * di + loadF(bias, (size_t)lane, f32);
  storeF(outp, obase + (size_t)node * 64 + lane, of32, lk(v));
}

// ---- edge scoring head ------------------------------------------------------
__global__ __launch_bounds__(256) void edge_head_kernel(void* __restrict__ dout,
                                                        const int* __restrict__ eli,
                                                        const void* __restrict__ ea,
                                                        const void* __restrict__ Wp,
                                                        const void* __restrict__ bp,
                                                        int EL, const int* __restrict__ flags) {
  int f32 = flags[0] != 0;
  int i64 = flags[1] == 0;
  int lane = threadIdx.x & 63;
  int wave = (blockIdx.x * blockDim.x + threadIdx.x) >> 6;
  if (wave >= EL) return;
  size_t hbase = (size_t)EL;
  float wp1 = loadF(Wp, (size_t)lane, f32);
  float wp2 = loadF(Wp, (size_t)(64 + lane), f32);
  float wp3 = lane < 8 ? loadF(Wp, (size_t)(128 + lane), f32) : 0.f;
  int s = loadI(eli, 0, (size_t)wave, i64);
  int d = loadI(eli, (size_t)EL, (size_t)wave, i64);
  float acc = loadF(dout, hbase + (size_t)s * 64 + lane, f32) * wp1 +
              loadF(dout, hbase + (size_t)d * 64 + lane, f32) * wp2;
  if (lane < 8) acc += loadF(ea, (size_t)wave * 8 + lane, f32) * wp3;
#pragma unroll
  for (int o = 32; o > 0; o >>= 1) acc += __shfl_down(acc, o, 64);
  if (lane == 0) storeF(dout, (size_t)wave, f32, acc + loadF(bp, 0, f32));
}

extern "C" void kernel_launch(void* const* d_in, const int* in_sizes, int n_in,
                              void* d_out, int out_size, void* d_ws, size_t ws_size,
                              hipStream_t stream) {
  const void* x   = d_in[0];
  const int* ei   = (const int*)d_in[1];
  const int* eli  = (const int*)d_in[2];
  const void* ea  = d_in[3];
  const void* W1  = d_in[4];
  const void* b1  = d_in[5];
  const void* W2  = d_in[6];
  const void* b2  = d_in[7];
  const void* Wg1 = d_in[8];
  const void* bg1 = d_in[9];
  const void* Wg2 = d_in[10];
  const void* bg2 = d_in[11];
  const void* Wp  = d_in[12];
  const void* bp  = d_in[13];

  const int Nn = in_sizes[0] / 256;
  const int E  = in_sizes[1] / 2;
  const int EL = in_sizes[2] / 2;
  const int NB = (Nn + BW - 1) >> BSHIFT;       // col buckets

  char* ws = (char*)d_ws;
  size_t off = 0;
  auto take = [&](size_t bytes) -> char* {
    char* p = ws + off;
    off = (off + bytes + 255) & ~(size_t)255;
    return p;
  };
  int*   flags  = (int*)take(256);
  int*   cur    = (int*)take((size_t)NB * NSTR * 4);   // contiguous after flags
  int*   bbase  = (int*)take((size_t)NB * 4);
  int*   rowptr = (int*)take((size_t)Nn * 4);
  float* dinv   = (float*)take((size_t)Nn * 4);
  int*   csr    = (int*)take((size_t)E * 4);
  int2*  rec    = (int2*)take((size_t)NB * NSTR * BCAP * 8);
  __hip_bfloat16* pW1 = (__hip_bfloat16*)take(256 * 128 * 2);
  __hip_bfloat16* pW2 = (__hip_bfloat16*)take(128 * 64 * 2);
  __hip_bfloat16* pG1 = (__hip_bfloat16*)take(64 * 64 * 2);
  __hip_bfloat16* pG2 = (__hip_bfloat16*)take(64 * 64 * 2);
  char* regionA = take((size_t)Nn * 128 * 4);   // h1(bf16) | later (xw fp32, y bf16)
  char* regionB = take((size_t)Nn * 64 * 4);    // h2(bf16) | later h3(bf16)
  __hip_bfloat16* h1 = (__hip_bfloat16*)regionA;
  float* xw  = (float*)regionA;
  __hip_bfloat16* y = (__hip_bfloat16*)(regionA + (size_t)Nn * 64 * 4);
  __hip_bfloat16* h2 = (__hip_bfloat16*)regionB;
  __hip_bfloat16* h3 = (__hip_bfloat16*)regionB;

  // flags + cur are contiguous -> one memset covers both
  hipMemsetAsync(flags, 0, 256 + (((size_t)NB * NSTR * 4 + 255) & ~(size_t)255), stream);
  detect_kernel<<<1, 256, 0, stream>>>((const unsigned short*)x, ei, flags);

  dim3 b64(64);
  pack_w_kernel<<<dim3(8, 8), b64, 0, stream>>>(W1, pW1, 128, flags);
  pack_w_kernel<<<dim3(4, 4), b64, 0, stream>>>(W2, pW2, 64, flags);
  pack_w_kernel<<<dim3(2, 4), b64, 0, stream>>>(Wg1, pG1, 64, flags);
  pack_w_kernel<<<dim3(2, 4), b64, 0, stream>>>(Wg2, pG2, 64, flags);

  // CSR build: LDS-staged binning -> scan -> place
  const int ldsbytes = NB * (8 + LCAP * 8);     // bcnt + gbase + bins
  const int nbin = (E + 256 * KEDGE - 1) / (256 * KEDGE);
  bin_kernel<<<nbin, 256, ldsbytes, stream>>>(ei, cur, rec, E, NB, flags);
  bucket_scan<<<1, 512, 0, stream>>>(cur, bbase, NB);
  place_kernel<<<NB, 256, 0, stream>>>(rec, cur, bbase, rowptr, csr, dinv, Nn);

  // tiled GEMMs: block = 32 rows, 4 waves = 4 col-partitions
  const int tblocks = (Nn + 31) / 32;
  gemm_tiled<8, 2, 1><<<tblocks, 256, 0, stream>>>(x, pW1, b1, h1, 1, nullptr, nullptr,
                                                   Nn, 128, 1, flags);
  gemm_tiled<4, 1, 0><<<tblocks, 256, 0, stream>>>(h1, pW2, b2, h2, 1, nullptr, nullptr,
                                                   Nn, 64, 1, flags);

  gemm_tiled<2, 1, 0><<<tblocks, 256, 0, stream>>>(h2, pG1, nullptr, xw, 0, y, dinv,
                                                   Nn, 64, 0, flags);
  gather_kernel<<<(Nn + 3) / 4, 256, 0, stream>>>(y, xw, csr, rowptr, dinv, bg1,
                                                  h3, 0, 0, Nn, flags);

  gemm_tiled<2, 1, 0><<<tblocks, 256, 0, stream>>>(h3, pG2, nullptr, xw, 0, y, dinv,
                                                   Nn, 64, 0, flags);
  gather_kernel<<<(Nn + 3) / 4, 256, 0, stream>>>(y, xw, csr, rowptr, dinv, bg2,
                                                  d_out, (size_t)EL, 1, Nn, flags);

  edge_head_kernel<<<(EL + 3) / 4, 256, 0, stream>>>(d_out, eli, ea, Wp, bp, EL, flags);
}

// Round 3
// 431.816 us; speedup vs baseline: 1.1960x; 1.1063x over previous
//
#include <hip/hip_runtime.h>
#include <hip/hip_bf16.h>

typedef __attribute__((ext_vector_type(8))) short bf16x8;
typedef __attribute__((ext_vector_type(4))) float f32x4;

#define BSHIFT 8          // cols per bucket = 256
#define BW 256
#define NSTR 8            // stripes (XCDs)
#define BCAP 768          // records per (bucket,stripe) stream; mean ~511
#define LCAP 24           // LDS records per bucket per round
#define KEDGE 16          // edges per thread per round (4096/block-round)

__device__ __forceinline__ float lk(float v) { return v > 0.f ? v : 0.01f * v; }

__device__ __forceinline__ short f2b(float v) {
  union { __hip_bfloat16 h; short s; } u;
  u.h = __float2bfloat16(v);
  return u.s;
}
__device__ __forceinline__ float loadF(const void* p, size_t i, int f32) {
  return f32 ? ((const float*)p)[i]
             : __bfloat162float(((const __hip_bfloat16*)p)[i]);
}
__device__ __forceinline__ void storeF(void* p, size_t i, int f32, float v) {
  if (f32) ((float*)p)[i] = v;
  else     ((__hip_bfloat16*)p)[i] = __float2bfloat16(v);
}
__device__ __forceinline__ int loadI(const int* p, size_t base, size_t e, int i64) {
  return i64 ? p[2 * (base + e)] : p[base + e];
}

// ---- dtype detection (device-side, graph-safe) ------------------------------
__global__ void detect_kernel(const unsigned short* __restrict__ x,
                              const int* __restrict__ ei, int* __restrict__ flags) {
  int t = threadIdx.x;
  unsigned short u = x[t];
  int ex = (u >> 7) & 0xFF;
  if (ex >= 0xC0) atomicOr(&flags[0], 1);          // fp32 viewed as bf16 -> wild exps
  if (t < 128 && ei[2 * t + 1] != 0) atomicOr(&flags[1], 1);  // nonzero -> int32
}

// ---- pack W [K,N] row-major -> MFMA B-fragment layout (bf16) ----------------
__global__ __launch_bounds__(64) void pack_w_kernel(const void* __restrict__ W,
                                                    __hip_bfloat16* __restrict__ P,
                                                    int N, const int* __restrict__ flags) {
  int f32 = flags[0] != 0;
  int ks = blockIdx.x, ct = blockIdx.y, KS = gridDim.x;
  int lane = threadIdx.x;
  int g = lane >> 4, m = lane & 15;
  size_t base = ((size_t)(ct * KS + ks) * 64 + (size_t)lane) * 8;
#pragma unroll
  for (int j = 0; j < 8; ++j)
    P[base + j] = __float2bfloat16(
        loadF(W, (size_t)(ks * 32 + g * 8 + j) * N + (size_t)(ct * 16 + m), f32));
}

// ---- tiled GEMM with global_load_lds A-staging ------------------------------
// Block = 4 waves, tile = 32 rows x K. Wave w owns col-partition w (CT tiles).
// LDS dest is linear; global SOURCE is pre-swizzled with the same XOR the
// ds reads use (rule 21: both-sides-or-neither).
//   f32  A: frag = 32B = chunk pair (c,c+1), xor = (row&3)<<1 (keeps pairs)
//   bf16 A: frag = 16B = 1 chunk,            xor = (row&7)

template <int ROWB, int F32>
__device__ __forceinline__ void stage_tile(const char* __restrict__ Ab, char* tile,
                                           int row0, int M, int w, int lane) {
  constexpr int CPR = ROWB / 16;     // 16B chunks per row
  constexpr int PERW = 32 * CPR / 4; // chunks per wave (multiple of 64)
#pragma unroll
  for (int i = 0; i < PERW; i += 64) {
    int p = w * PERW + i + lane;
    int r = p / CPR;
    int pc = p - r * CPR;
    int xv = F32 ? ((r & 3) << 1) : (r & 7);
    int gr = row0 + r; if (gr >= M) gr = M - 1;
    const char* src = Ab + (size_t)gr * ROWB + (size_t)(pc ^ xv) * 16;
    char* dst = tile + (size_t)(w * PERW + i) * 16;   // wave-uniform base
    __builtin_amdgcn_global_load_lds(
        (const __attribute__((address_space(1))) void*)src,
        (__attribute__((address_space(3))) void*)dst, 16, 0, 0);
  }
}

template <int KS, int CT, int F32>
__device__ __forceinline__ void tile_core(const char* tile,
                                          const __hip_bfloat16* __restrict__ bbase,
                                          int m, int g, f32x4 (&accs)[2][CT]) {
  constexpr int ROWB = KS * 32 * (F32 ? 4 : 2);
#pragma unroll
  for (int ks = 0; ks < KS; ++ks) {
    bf16x8 a[2];
#pragma unroll
    for (int t = 0; t < 2; ++t) {
      int r = t * 16 + m;
      if constexpr (F32) {
        int c = ks * 8 + g * 2;                 // chunk pair c, c+1
        int xv = (r & 3) << 1;
        float4 q0 = *(const float4*)(tile + (size_t)r * ROWB + (size_t)((c ^ xv) * 16));
        float4 q1 = *(const float4*)(tile + (size_t)r * ROWB + (size_t)(((c + 1) ^ xv) * 16));
        a[t][0] = f2b(q0.x); a[t][1] = f2b(q0.y); a[t][2] = f2b(q0.z); a[t][3] = f2b(q0.w);
        a[t][4] = f2b(q1.x); a[t][5] = f2b(q1.y); a[t][6] = f2b(q1.z); a[t][7] = f2b(q1.w);
      } else {
        int c = ks * 4 + g;                     // single 16B chunk
        int xv = r & 7;
        a[t] = *(const bf16x8*)(tile + (size_t)r * ROWB + (size_t)((c ^ xv) * 16));
      }
    }
    const __hip_bfloat16* bb = bbase + (size_t)ks * 64 * 8;
#pragma unroll
    for (int cc = 0; cc < CT; ++cc) {
      bf16x8 b = *(const bf16x8*)(bb + (size_t)cc * KS * 64 * 8);
#pragma unroll
      for (int t = 0; t < 2; ++t)
        accs[t][cc] = __builtin_amdgcn_mfma_f32_16x16x32_bf16(a[t], b, accs[t][cc], 0, 0, 0);
    }
  }
}

// AMODE: 0 = A always bf16; 1 = A dtype from flags[0] (fp32 or bf16)
template <int KS, int CT, int AMODE>
__global__ __launch_bounds__(256) void gemm_tiled(const void* __restrict__ A,
                                                  const __hip_bfloat16* __restrict__ Bp,
                                                  const void* __restrict__ bias,
                                                  void* __restrict__ Out, int out_bf16,
                                                  __hip_bfloat16* __restrict__ Yout,
                                                  const float* __restrict__ dinv,
                                                  int M, int N, int act,
                                                  const int* __restrict__ flags) {
  constexpr int K = KS * 32;
  constexpr int LDSB = 32 * K * (AMODE ? 4 : 2);
  __shared__ char tile[LDSB];
  int f32 = AMODE ? (flags[0] != 0) : 0;
  int lane = threadIdx.x & 63;
  int w = threadIdx.x >> 6;                     // wave id = col partition
  int m = lane & 15, g = lane >> 4;
  int row0 = blockIdx.x * 32;

  const char* Ab = (const char*)A;
  if (f32) stage_tile<K * 4, 1>(Ab, tile, row0, M, w, lane);
  else     stage_tile<K * 2, 0>(Ab, tile, row0, M, w, lane);
  __syncthreads();

  const __hip_bfloat16* bbase = Bp + ((size_t)(w * CT) * KS * 64 + (size_t)lane) * 8;
  f32x4 accs[2][CT];
#pragma unroll
  for (int t = 0; t < 2; ++t)
#pragma unroll
    for (int cc = 0; cc < CT; ++cc) accs[t][cc] = (f32x4){0, 0, 0, 0};

  if (f32) tile_core<KS, CT, 1>(tile, bbase, m, g, accs);
  else     tile_core<KS, CT, 0>(tile, bbase, m, g, accs);

  // epilogue
  float bv[CT];
#pragma unroll
  for (int cc = 0; cc < CT; ++cc)
    bv[cc] = bias ? loadF(bias, (size_t)((w * CT + cc) * 16 + m), flags[0] != 0) : 0.f;
#pragma unroll
  for (int t = 0; t < 2; ++t) {
#pragma unroll
    for (int r = 0; r < 4; ++r) {
      int ro = row0 + t * 16 + g * 4 + r;
      if (ro < M) {
        float di = Yout ? dinv[ro] : 0.f;
#pragma unroll
        for (int cc = 0; cc < CT; ++cc) {
          int col = (w * CT + cc) * 16 + m;
          float v = accs[t][cc][r] + bv[cc];
          if (act) v = lk(v);
          if (out_bf16) ((__hip_bfloat16*)Out)[(size_t)ro * N + col] = __float2bfloat16(v);
          else          ((float*)Out)[(size_t)ro * N + col] = v;
          if (Yout) Yout[(size_t)ro * N + col] = __float2bfloat16(v * di);
        }
      }
    }
  }
}

// ---- CSR build pass A: LDS-staged binning, batched stream flush -------------
// LDS: bcnt[NB] | gbase[NB] | bins[NB*LCAP] (int2)
__global__ __launch_bounds__(256) void bin_kernel(const int* __restrict__ ei,
                                                  int* __restrict__ cur,
                                                  int2* __restrict__ rec,
                                                  int E, int NB,
                                                  const int* __restrict__ flags) {
  extern __shared__ int lds[];
  int* bcnt = lds;
  int* gbase = lds + NB;
  int2* bins = (int2*)(lds + 2 * NB);
  int i64 = flags[1] == 0;
  // real XCD id (hwreg 20); any value is correctness-safe after &7
  int stripe = __builtin_amdgcn_s_getreg(63508) & (NSTR - 1);
  int t = threadIdx.x;
  const int perRound = 256 * KEDGE;
  for (int base = blockIdx.x * perRound; base < E; base += gridDim.x * perRound) {
    for (int b = t; b < NB; b += 256) bcnt[b] = 0;
    __syncthreads();
    // bin into LDS
#pragma unroll 1
    for (int k = 0; k < KEDGE; ++k) {
      int i = base + k * 256 + t;
      if (i < E) {
        int r = loadI(ei, 0, (size_t)i, i64);
        int c = loadI(ei, (size_t)E, (size_t)i, i64);
        int b = c >> BSHIFT;
        int pos = atomicAdd(&bcnt[b], 1);
        if (pos < LCAP) {
          bins[b * LCAP + pos] = make_int2(r, c);
        } else {                                   // rare overflow: direct append
          int bs = b * NSTR + stripe;
          int slot = atomicAdd(&cur[bs], 1);
          if (slot < BCAP) rec[(size_t)bs * BCAP + slot] = make_int2(r, c);
        }
      }
    }
    __syncthreads();
    // reserve stream ranges (parallel atomics, no serialized chain)
    for (int b = t; b < NB; b += 256) {
      int n = min(bcnt[b], LCAP);
      if (n > 0) gbase[b] = atomicAdd(&cur[b * NSTR + stripe], n);
    }
    __syncthreads();
    // contiguous copy LDS -> stream
    int lane = t & 63, w = t >> 6;
    for (int b = w; b < NB; b += 4) {
      int n = min(bcnt[b], LCAP);
      if (n == 0) continue;
      int gb = gbase[b];
      size_t sb = (size_t)(b * NSTR + stripe) * BCAP;
      if (lane < n && gb + lane < BCAP)
        rec[sb + gb + lane] = bins[b * LCAP + lane];
    }
    __syncthreads();
  }
}

// exclusive prefix over bucket totals (single block; NB <= 512)
__global__ __launch_bounds__(512) void bucket_scan(const int* __restrict__ cur,
                                                   int* __restrict__ bbase, int NB) {
  __shared__ int lds[512];
  int t = threadIdx.x;
  int tot = 0;
  if (t < NB)
#pragma unroll
    for (int s = 0; s < NSTR; ++s) tot += min(cur[t * NSTR + s], BCAP);
  lds[t] = tot; __syncthreads();
  for (int o = 1; o < 512; o <<= 1) {
    int a = (t >= o) ? lds[t - o] : 0; __syncthreads();
    lds[t] += a; __syncthreads();
  }
  if (t < NB) bbase[t] = lds[t] - tot;
}

// Pass B: one block per bucket. LDS count -> scan -> rowptr/dinv -> place
__global__ __launch_bounds__(256) void place_kernel(const int2* __restrict__ rec,
                                                    const int* __restrict__ cur,
                                                    const int* __restrict__ bbase,
                                                    int* __restrict__ rowptr,
                                                    int* __restrict__ csr,
                                                    float* __restrict__ dinv, int Nn) {
  int b = blockIdx.x;
  int lo = b << BSHIFT;
  int t = threadIdx.x;
  __shared__ int cnt[BW];
  __shared__ int sc[BW];
  __shared__ int cursor[BW];
  cnt[t] = 0;
  __syncthreads();
#pragma unroll 1
  for (int s = 0; s < NSTR; ++s) {
    int n = min(cur[b * NSTR + s], BCAP);
    const int2* rp = rec + (size_t)(b * NSTR + s) * BCAP;
    for (int j = t; j < n; j += 256) atomicAdd(&cnt[rp[j].y - lo], 1);
  }
  __syncthreads();
  int v = cnt[t];
  sc[t] = v; __syncthreads();
  for (int o = 1; o < BW; o <<= 1) {
    int a = (t >= o) ? sc[t - o] : 0; __syncthreads();
    sc[t] += a; __syncthreads();
  }
  int base = bbase[b];
  int col = lo + t;
  if (col < Nn) {
    rowptr[col] = base + sc[t];                 // segment END
    dinv[col] = rsqrtf((float)v + 1.0f);
  }
  cursor[t] = base + sc[t] - v;                 // segment start
  __syncthreads();
#pragma unroll 1
  for (int s = 0; s < NSTR; ++s) {
    int n = min(cur[b * NSTR + s], BCAP);
    const int2* rp = rec + (size_t)(b * NSTR + s) * BCAP;
    for (int j = t; j < n; j += 256) {
      int2 e = rp[j];
      int pos = atomicAdd(&cursor[e.y - lo], 1);
      csr[pos] = e.x;
    }
  }
}

// ---- pull-mode aggregation + self-term + bias + leaky, fused ----------------
// Optionally also reduces per-node edge-head scores: ssrc[n]=h[n].wp1,
// sdst[n]=h[n].wp2 (fused so h is never re-read by the edge head).
__global__ __launch_bounds__(256) void gather_kernel(const __hip_bfloat16* __restrict__ y,
                                                     const float* __restrict__ xw,
                                                     const int* __restrict__ csr,
                                                     const int* __restrict__ rowptr,
                                                     const float* __restrict__ dinv,
                                                     const void* __restrict__ bias,
                                                     void* __restrict__ outp, size_t obase,
                                                     int out_use_flag, int Nn,
                                                     float* __restrict__ ssrc,
                                                     float* __restrict__ sdst,
                                                     const void* __restrict__ Wp,
                                                     const int* __restrict__ flags) {
  int f32 = flags[0] != 0;
  int of32 = out_use_flag ? f32 : 0;    // intermediate h3 stored bf16
  int lane = threadIdx.x & 63;
  int node = (blockIdx.x * blockDim.x + threadIdx.x) >> 6;
  if (node >= Nn) return;
  int s = (node == 0) ? 0 : rowptr[node - 1];
  int e = rowptr[node];
  float a0 = 0, a1 = 0, a2 = 0, a3 = 0;
  for (int base = s; base < e; base += 64) {
    int cnt = e - base; if (cnt > 64) cnt = 64;
    int rl = (base + lane < e) ? csr[base + lane] : 0;
    int j = 0;
    for (; j + 4 <= cnt; j += 4) {
      int r0 = __shfl(rl, j, 64), r1 = __shfl(rl, j + 1, 64);
      int r2 = __shfl(rl, j + 2, 64), r3 = __shfl(rl, j + 3, 64);
      a0 += __bfloat162float(y[(size_t)r0 * 64 + lane]);
      a1 += __bfloat162float(y[(size_t)r1 * 64 + lane]);
      a2 += __bfloat162float(y[(size_t)r2 * 64 + lane]);
      a3 += __bfloat162float(y[(size_t)r3 * 64 + lane]);
    }
    for (; j < cnt; ++j) {
      int r0 = __shfl(rl, j, 64);
      a0 += __bfloat162float(y[(size_t)r0 * 64 + lane]);
    }
  }
  float acc = (a0 + a1) + (a2 + a3);
  float di = dinv[node];
  float v = di * acc + xw[(size_t)node * 64 + lane] * di * di + loadF(bias, (size_t)lane, f32);
  v = lk(v);
  storeF(outp, obase + (size_t)node * 64 + lane, of32, v);
  if (ssrc) {
    float p1 = v * loadF(Wp, (size_t)lane, f32);
    float p2 = v * loadF(Wp, (size_t)(64 + lane), f32);
#pragma unroll
    for (int o = 32; o > 0; o >>= 1) {
      p1 += __shfl_down(p1, o, 64);
      p2 += __shfl_down(p2, o, 64);
    }
    if (lane == 0) { ssrc[node] = p1; sdst[node] = p2; }
  }
}

// ---- edge scoring head: one THREAD per edge, scores precomputed -------------
__global__ __launch_bounds__(256) void edge_head_kernel(void* __restrict__ dout,
                                                        const int* __restrict__ eli,
                                                        const void* __restrict__ ea,
                                                        const float* __restrict__ ssrc,
                                                        const float* __restrict__ sdst,
                                                        const void* __restrict__ Wp,
                                                        const void* __restrict__ bp,
                                                        int EL, const int* __restrict__ flags) {
  int f32 = flags[0] != 0;
  int i64 = flags[1] == 0;
  int tid = blockIdx.x * blockDim.x + threadIdx.x;
  if (tid >= EL) return;
  int s = loadI(eli, 0, (size_t)tid, i64);
  int d = loadI(eli, (size_t)EL, (size_t)tid, i64);
  float acc = ssrc[s] + sdst[d] + loadF(bp, 0, f32);
  if (f32) {
    const float* eap = (const float*)ea + (size_t)tid * 8;
    float4 u0 = *(const float4*)eap;
    float4 u1 = *(const float4*)(eap + 4);
    acc += u0.x * loadF(Wp, 128, 1) + u0.y * loadF(Wp, 129, 1) +
           u0.z * loadF(Wp, 130, 1) + u0.w * loadF(Wp, 131, 1) +
           u1.x * loadF(Wp, 132, 1) + u1.y * loadF(Wp, 133, 1) +
           u1.z * loadF(Wp, 134, 1) + u1.w * loadF(Wp, 135, 1);
  } else {
    bf16x8 u = *(const bf16x8*)((const __hip_bfloat16*)ea + (size_t)tid * 8);
#pragma unroll
    for (int j = 0; j < 8; ++j) {
      union { short s; __hip_bfloat16 h; } cv; cv.s = u[j];
      acc += __bfloat162float(cv.h) * loadF(Wp, (size_t)(128 + j), 0);
    }
  }
  storeF(dout, (size_t)tid, f32, acc);
}

extern "C" void kernel_launch(void* const* d_in, const int* in_sizes, int n_in,
                              void* d_out, int out_size, void* d_ws, size_t ws_size,
                              hipStream_t stream) {
  const void* x   = d_in[0];
  const int* ei   = (const int*)d_in[1];
  const int* eli  = (const int*)d_in[2];
  const void* ea  = d_in[3];
  const void* W1  = d_in[4];
  const void* b1  = d_in[5];
  const void* W2  = d_in[6];
  const void* b2  = d_in[7];
  const void* Wg1 = d_in[8];
  const void* bg1 = d_in[9];
  const void* Wg2 = d_in[10];
  const void* bg2 = d_in[11];
  const void* Wp  = d_in[12];
  const void* bp  = d_in[13];

  const int Nn = in_sizes[0] / 256;
  const int E  = in_sizes[1] / 2;
  const int EL = in_sizes[2] / 2;
  const int NB = (Nn + BW - 1) >> BSHIFT;       // col buckets

  char* ws = (char*)d_ws;
  size_t off = 0;
  auto take = [&](size_t bytes) -> char* {
    char* p = ws + off;
    off = (off + bytes + 255) & ~(size_t)255;
    return p;
  };
  int*   flags  = (int*)take(256);
  int*   cur    = (int*)take((size_t)NB * NSTR * 4);   // contiguous after flags
  int*   bbase  = (int*)take((size_t)NB * 4);
  int*   rowptr = (int*)take((size_t)Nn * 4);
  float* dinv   = (float*)take((size_t)Nn * 4);
  float* ssrc   = (float*)take((size_t)Nn * 4);
  float* sdst   = (float*)take((size_t)Nn * 4);
  int*   csr    = (int*)take((size_t)E * 4);
  int2*  rec    = (int2*)take((size_t)NB * NSTR * BCAP * 8);
  __hip_bfloat16* pW1 = (__hip_bfloat16*)take(256 * 128 * 2);
  __hip_bfloat16* pW2 = (__hip_bfloat16*)take(128 * 64 * 2);
  __hip_bfloat16* pG1 = (__hip_bfloat16*)take(64 * 64 * 2);
  __hip_bfloat16* pG2 = (__hip_bfloat16*)take(64 * 64 * 2);
  char* regionA = take((size_t)Nn * 128 * 4);   // h1(bf16) | later (xw fp32, y bf16)
  char* regionB = take((size_t)Nn * 64 * 4);    // h2(bf16) | later h3(bf16)
  __hip_bfloat16* h1 = (__hip_bfloat16*)regionA;
  float* xw  = (float*)regionA;
  __hip_bfloat16* y = (__hip_bfloat16*)(regionA + (size_t)Nn * 64 * 4);
  __hip_bfloat16* h2 = (__hip_bfloat16*)regionB;
  __hip_bfloat16* h3 = (__hip_bfloat16*)regionB;

  // flags + cur are contiguous -> one memset covers both
  hipMemsetAsync(flags, 0, 256 + (((size_t)NB * NSTR * 4 + 255) & ~(size_t)255), stream);
  detect_kernel<<<1, 256, 0, stream>>>((const unsigned short*)x, ei, flags);

  dim3 b64(64);
  pack_w_kernel<<<dim3(8, 8), b64, 0, stream>>>(W1, pW1, 128, flags);
  pack_w_kernel<<<dim3(4, 4), b64, 0, stream>>>(W2, pW2, 64, flags);
  pack_w_kernel<<<dim3(2, 4), b64, 0, stream>>>(Wg1, pG1, 64, flags);
  pack_w_kernel<<<dim3(2, 4), b64, 0, stream>>>(Wg2, pG2, 64, flags);

  // CSR build: LDS-staged binning -> scan -> place
  const int ldsbytes = NB * (8 + LCAP * 8);     // bcnt + gbase + bins
  const int nbin = (E + 256 * KEDGE - 1) / (256 * KEDGE);
  bin_kernel<<<nbin, 256, ldsbytes, stream>>>(ei, cur, rec, E, NB, flags);
  bucket_scan<<<1, 512, 0, stream>>>(cur, bbase, NB);
  place_kernel<<<NB, 256, 0, stream>>>(rec, cur, bbase, rowptr, csr, dinv, Nn);

  // tiled GEMMs: block = 32 rows, 4 waves = 4 col-partitions
  const int tblocks = (Nn + 31) / 32;
  gemm_tiled<8, 2, 1><<<tblocks, 256, 0, stream>>>(x, pW1, b1, h1, 1, nullptr, nullptr,
                                                   Nn, 128, 1, flags);
  gemm_tiled<4, 1, 0><<<tblocks, 256, 0, stream>>>(h1, pW2, b2, h2, 1, nullptr, nullptr,
                                                   Nn, 64, 1, flags);

  gemm_tiled<2, 1, 0><<<tblocks, 256, 0, stream>>>(h2, pG1, nullptr, xw, 0, y, dinv,
                                                   Nn, 64, 0, flags);
  gather_kernel<<<(Nn + 3) / 4, 256, 0, stream>>>(y, xw, csr, rowptr, dinv, bg1,
                                                  h3, 0, 0, Nn,
                                                  nullptr, nullptr, nullptr, flags);

  gemm_tiled<2, 1, 0><<<tblocks, 256, 0, stream>>>(h3, pG2, nullptr, xw, 0, y, dinv,
                                                   Nn, 64, 0, flags);
  gather_kernel<<<(Nn + 3) / 4, 256, 0, stream>>>(y, xw, csr, rowptr, dinv, bg2,
                                                  d_out, (size_t)EL, 1, Nn,
                                                  ssrc, sdst, Wp, flags);

  edge_head_kernel<<<(EL + 255) / 256, 256, 0, stream>>>(d_out, eli, ea, ssrc, sdst,
                                                         Wp, bp, EL, flags);
}

// Round 4
// 417.479 us; speedup vs baseline: 1.2371x; 1.0343x over previous
//
#include <hip/hip_runtime.h>
#include <hip/hip_bf16.h>

typedef __attribute__((ext_vector_type(8))) short bf16x8;
typedef __attribute__((ext_vector_type(4))) float f32x4;

#define BSHIFT 8          // cols per bucket = 256
#define BW 256
#define NSTR 8            // stripes (XCDs)
#define BCAP 768          // records per (bucket,stripe) stream; mean ~511
#define LCAP 24           // LDS records per bucket per round
#define KEDGE 16          // edges per thread per round (4096/block-round)

__device__ __forceinline__ float lk(float v) { return v > 0.f ? v : 0.01f * v; }

__device__ __forceinline__ short f2b(float v) {
  union { __hip_bfloat16 h; short s; } u;
  u.h = __float2bfloat16(v);
  return u.s;
}
__device__ __forceinline__ float loadF(const void* p, size_t i, int f32) {
  return f32 ? ((const float*)p)[i]
             : __bfloat162float(((const __hip_bfloat16*)p)[i]);
}
__device__ __forceinline__ void storeF(void* p, size_t i, int f32, float v) {
  if (f32) ((float*)p)[i] = v;
  else     ((__hip_bfloat16*)p)[i] = __float2bfloat16(v);
}
__device__ __forceinline__ int loadI(const int* p, size_t base, size_t e, int i64) {
  return i64 ? p[2 * (base + e)] : p[base + e];
}
// bf16 pair (u32) -> two floats via bit ops (no cvt instruction)
__device__ __forceinline__ float blo(unsigned u) {
  union { unsigned u; float f; } c; c.u = u << 16; return c.f;
}
__device__ __forceinline__ float bhi(unsigned u) {
  union { unsigned u; float f; } c; c.u = u & 0xffff0000u; return c.f;
}

// ---- dtype detection (device-side, graph-safe) ------------------------------
__global__ void detect_kernel(const unsigned short* __restrict__ x,
                              const int* __restrict__ ei, int* __restrict__ flags) {
  int t = threadIdx.x;
  unsigned short u = x[t];
  int ex = (u >> 7) & 0xFF;
  if (ex >= 0xC0) atomicOr(&flags[0], 1);          // fp32 viewed as bf16 -> wild exps
  if (t < 128 && ei[2 * t + 1] != 0) atomicOr(&flags[1], 1);  // nonzero -> int32
}

// ---- pack W [K,N] row-major -> MFMA B-fragment layout (bf16) ----------------
__global__ __launch_bounds__(64) void pack_w_kernel(const void* __restrict__ W,
                                                    __hip_bfloat16* __restrict__ P,
                                                    int N, const int* __restrict__ flags) {
  int f32 = flags[0] != 0;
  int ks = blockIdx.x, ct = blockIdx.y, KS = gridDim.x;
  int lane = threadIdx.x;
  int g = lane >> 4, m = lane & 15;
  size_t base = ((size_t)(ct * KS + ks) * 64 + (size_t)lane) * 8;
#pragma unroll
  for (int j = 0; j < 8; ++j)
    P[base + j] = __float2bfloat16(
        loadF(W, (size_t)(ks * 32 + g * 8 + j) * N + (size_t)(ct * 16 + m), f32));
}

// ---- tiled GEMM with global_load_lds A-staging ------------------------------
// Block = 4 waves, tile = 32 rows x K. Wave w owns col-partition w (CT tiles).
// LDS dest is linear; global SOURCE is pre-swizzled with the same XOR the
// ds reads use (rule 21: both-sides-or-neither).
//   f32  A: frag = 32B = chunk pair (c,c+1), xor = (row&3)<<1 (keeps pairs)
//   bf16 A: frag = 16B = 1 chunk,            xor = (row&7)

template <int ROWB, int F32>
__device__ __forceinline__ void stage_tile(const char* __restrict__ Ab, char* tile,
                                           int row0, int M, int w, int lane) {
  constexpr int CPR = ROWB / 16;     // 16B chunks per row
  constexpr int PERW = 32 * CPR / 4; // chunks per wave (multiple of 64)
#pragma unroll
  for (int i = 0; i < PERW; i += 64) {
    int p = w * PERW + i + lane;
    int r = p / CPR;
    int pc = p - r * CPR;
    int xv = F32 ? ((r & 3) << 1) : (r & 7);
    int gr = row0 + r; if (gr >= M) gr = M - 1;
    const char* src = Ab + (size_t)gr * ROWB + (size_t)(pc ^ xv) * 16;
    char* dst = tile + (size_t)(w * PERW + i) * 16;   // wave-uniform base
    __builtin_amdgcn_global_load_lds(
        (const __attribute__((address_space(1))) void*)src,
        (__attribute__((address_space(3))) void*)dst, 16, 0, 0);
  }
}

template <int KS, int CT, int F32>
__device__ __forceinline__ void tile_core(const char* tile,
                                          const __hip_bfloat16* __restrict__ bbase,
                                          int m, int g, f32x4 (&accs)[2][CT]) {
  constexpr int ROWB = KS * 32 * (F32 ? 4 : 2);
#pragma unroll
  for (int ks = 0; ks < KS; ++ks) {
    bf16x8 a[2];
#pragma unroll
    for (int t = 0; t < 2; ++t) {
      int r = t * 16 + m;
      if constexpr (F32) {
        int c = ks * 8 + g * 2;                 // chunk pair c, c+1
        int xv = (r & 3) << 1;
        float4 q0 = *(const float4*)(tile + (size_t)r * ROWB + (size_t)((c ^ xv) * 16));
        float4 q1 = *(const float4*)(tile + (size_t)r * ROWB + (size_t)(((c + 1) ^ xv) * 16));
        a[t][0] = f2b(q0.x); a[t][1] = f2b(q0.y); a[t][2] = f2b(q0.z); a[t][3] = f2b(q0.w);
        a[t][4] = f2b(q1.x); a[t][5] = f2b(q1.y); a[t][6] = f2b(q1.z); a[t][7] = f2b(q1.w);
      } else {
        int c = ks * 4 + g;                     // single 16B chunk
        int xv = r & 7;
        a[t] = *(const bf16x8*)(tile + (size_t)r * ROWB + (size_t)((c ^ xv) * 16));
      }
    }
    const __hip_bfloat16* bb = bbase + (size_t)ks * 64 * 8;
#pragma unroll
    for (int cc = 0; cc < CT; ++cc) {
      bf16x8 b = *(const bf16x8*)(bb + (size_t)cc * KS * 64 * 8);
#pragma unroll
      for (int t = 0; t < 2; ++t)
        accs[t][cc] = __builtin_amdgcn_mfma_f32_16x16x32_bf16(a[t], b, accs[t][cc], 0, 0, 0);
    }
  }
}

// AMODE: 0 = A always bf16; 1 = A dtype from flags[0] (fp32 or bf16)
// Out may be nullptr (write only Yout = bf16(v * dinv[row]))
template <int KS, int CT, int AMODE>
__global__ __launch_bounds__(256) void gemm_tiled(const void* __restrict__ A,
                                                  const __hip_bfloat16* __restrict__ Bp,
                                                  const void* __restrict__ bias,
                                                  void* __restrict__ Out, int out_bf16,
                                                  __hip_bfloat16* __restrict__ Yout,
                                                  const float* __restrict__ dinv,
                                                  int M, int N, int act,
                                                  const int* __restrict__ flags) {
  constexpr int K = KS * 32;
  constexpr int LDSB = 32 * K * (AMODE ? 4 : 2);
  __shared__ char tile[LDSB];
  int f32 = AMODE ? (flags[0] != 0) : 0;
  int lane = threadIdx.x & 63;
  int w = threadIdx.x >> 6;                     // wave id = col partition
  int m = lane & 15, g = lane >> 4;
  int row0 = blockIdx.x * 32;

  const char* Ab = (const char*)A;
  if (f32) stage_tile<K * 4, 1>(Ab, tile, row0, M, w, lane);
  else     stage_tile<K * 2, 0>(Ab, tile, row0, M, w, lane);
  __syncthreads();

  const __hip_bfloat16* bbase = Bp + ((size_t)(w * CT) * KS * 64 + (size_t)lane) * 8;
  f32x4 accs[2][CT];
#pragma unroll
  for (int t = 0; t < 2; ++t)
#pragma unroll
    for (int cc = 0; cc < CT; ++cc) accs[t][cc] = (f32x4){0, 0, 0, 0};

  if (f32) tile_core<KS, CT, 1>(tile, bbase, m, g, accs);
  else     tile_core<KS, CT, 0>(tile, bbase, m, g, accs);

  // epilogue
  float bv[CT];
#pragma unroll
  for (int cc = 0; cc < CT; ++cc)
    bv[cc] = bias ? loadF(bias, (size_t)((w * CT + cc) * 16 + m), flags[0] != 0) : 0.f;
#pragma unroll
  for (int t = 0; t < 2; ++t) {
#pragma unroll
    for (int r = 0; r < 4; ++r) {
      int ro = row0 + t * 16 + g * 4 + r;
      if (ro < M) {
        float di = Yout ? dinv[ro] : 0.f;
#pragma unroll
        for (int cc = 0; cc < CT; ++cc) {
          int col = (w * CT + cc) * 16 + m;
          float v = accs[t][cc][r] + bv[cc];
          if (act) v = lk(v);
          if (Out) {
            if (out_bf16) ((__hip_bfloat16*)Out)[(size_t)ro * N + col] = __float2bfloat16(v);
            else          ((float*)Out)[(size_t)ro * N + col] = v;
          }
          if (Yout) Yout[(size_t)ro * N + col] = __float2bfloat16(v * di);
        }
      }
    }
  }
}

// ---- CSR build pass A: LDS-staged binning, batched stream flush -------------
// LDS: bcnt[NB] | gbase[NB] | bins[NB*LCAP] (int2)
__global__ __launch_bounds__(256) void bin_kernel(const int* __restrict__ ei,
                                                  int* __restrict__ cur,
                                                  int2* __restrict__ rec,
                                                  int E, int NB,
                                                  const int* __restrict__ flags) {
  extern __shared__ int lds[];
  int* bcnt = lds;
  int* gbase = lds + NB;
  int2* bins = (int2*)(lds + 2 * NB);
  int i64 = flags[1] == 0;
  // real XCD id (hwreg 20); any value is correctness-safe after &7
  int stripe = __builtin_amdgcn_s_getreg(63508) & (NSTR - 1);
  int t = threadIdx.x;
  const int perRound = 256 * KEDGE;
  for (int base = blockIdx.x * perRound; base < E; base += gridDim.x * perRound) {
    for (int b = t; b < NB; b += 256) bcnt[b] = 0;
    __syncthreads();
    // bin into LDS
#pragma unroll 1
    for (int k = 0; k < KEDGE; ++k) {
      int i = base + k * 256 + t;
      if (i < E) {
        int r = loadI(ei, 0, (size_t)i, i64);
        int c = loadI(ei, (size_t)E, (size_t)i, i64);
        int b = c >> BSHIFT;
        int pos = atomicAdd(&bcnt[b], 1);
        if (pos < LCAP) {
          bins[b * LCAP + pos] = make_int2(r, c);
        } else {                                   // rare overflow: direct append
          int bs = b * NSTR + stripe;
          int slot = atomicAdd(&cur[bs], 1);
          if (slot < BCAP) rec[(size_t)bs * BCAP + slot] = make_int2(r, c);
        }
      }
    }
    __syncthreads();
    // reserve stream ranges (parallel atomics, no serialized chain)
    for (int b = t; b < NB; b += 256) {
      int n = min(bcnt[b], LCAP);
      if (n > 0) gbase[b] = atomicAdd(&cur[b * NSTR + stripe], n);
    }
    __syncthreads();
    // contiguous copy LDS -> stream
    int lane = t & 63, w = t >> 6;
    for (int b = w; b < NB; b += 4) {
      int n = min(bcnt[b], LCAP);
      if (n == 0) continue;
      int gb = gbase[b];
      size_t sb = (size_t)(b * NSTR + stripe) * BCAP;
      if (lane < n && gb + lane < BCAP)
        rec[sb + gb + lane] = bins[b * LCAP + lane];
    }
    __syncthreads();
  }
}

// exclusive prefix over bucket totals (single block; NB <= 512)
__global__ __launch_bounds__(512) void bucket_scan(const int* __restrict__ cur,
                                                   int* __restrict__ bbase, int NB) {
  __shared__ int lds[512];
  int t = threadIdx.x;
  int tot = 0;
  if (t < NB)
#pragma unroll
    for (int s = 0; s < NSTR; ++s) tot += min(cur[t * NSTR + s], BCAP);
  lds[t] = tot; __syncthreads();
  for (int o = 1; o < 512; o <<= 1) {
    int a = (t >= o) ? lds[t - o] : 0; __syncthreads();
    lds[t] += a; __syncthreads();
  }
  if (t < NB) bbase[t] = lds[t] - tot;
}

// Pass B: one block per bucket. LDS count -> scan -> rowptr/dinv -> place
__global__ __launch_bounds__(256) void place_kernel(const int2* __restrict__ rec,
                                                    const int* __restrict__ cur,
                                                    const int* __restrict__ bbase,
                                                    int* __restrict__ rowptr,
                                                    int* __restrict__ csr,
                                                    float* __restrict__ dinv, int Nn) {
  int b = blockIdx.x;
  int lo = b << BSHIFT;
  int t = threadIdx.x;
  __shared__ int cnt[BW];
  __shared__ int sc[BW];
  __shared__ int cursor[BW];
  cnt[t] = 0;
  __syncthreads();
#pragma unroll 1
  for (int s = 0; s < NSTR; ++s) {
    int n = min(cur[b * NSTR + s], BCAP);
    const int2* rp = rec + (size_t)(b * NSTR + s) * BCAP;
    for (int j = t; j < n; j += 256) atomicAdd(&cnt[rp[j].y - lo], 1);
  }
  __syncthreads();
  int v = cnt[t];
  sc[t] = v; __syncthreads();
  for (int o = 1; o < BW; o <<= 1) {
    int a = (t >= o) ? sc[t - o] : 0; __syncthreads();
    sc[t] += a; __syncthreads();
  }
  int base = bbase[b];
  int col = lo + t;
  if (col < Nn) {
    rowptr[col] = base + sc[t];                 // segment END
    dinv[col] = rsqrtf((float)v + 1.0f);
  }
  cursor[t] = base + sc[t] - v;                 // segment start
  __syncthreads();
#pragma unroll 1
  for (int s = 0; s < NSTR; ++s) {
    int n = min(cur[b * NSTR + s], BCAP);
    const int2* rp = rec + (size_t)(b * NSTR + s) * BCAP;
    for (int j = t; j < n; j += 256) {
      int2 e = rp[j];
      int pos = atomicAdd(&cursor[e.y - lo], 1);
      csr[pos] = e.x;
    }
  }
}

// ---- pull-mode aggregation + self-term + bias + leaky, fused ----------------
// Wave split into two 32-lane halves; each half handles a different edge with
// ushort2 (feature-pair) loads. Self term uses y[node]*di == xw*di*di (one
// extra bf16 rounding, scaled by 1/(deg+1) -> negligible).
// Optionally reduces edge-head scores ssrc[n]=h[n].wp1, sdst[n]=h[n].wp2.
__global__ __launch_bounds__(256) void gather_kernel(const __hip_bfloat16* __restrict__ y,
                                                     const int* __restrict__ csr,
                                                     const int* __restrict__ rowptr,
                                                     const float* __restrict__ dinv,
                                                     const void* __restrict__ bias,
                                                     void* __restrict__ outp, size_t obase,
                                                     int out_use_flag, int Nn,
                                                     float* __restrict__ ssrc,
                                                     float* __restrict__ sdst,
                                                     const void* __restrict__ Wp,
                                                     const int* __restrict__ flags) {
  int f32 = flags[0] != 0;
  int of32 = out_use_flag ? f32 : 0;    // intermediate h3 stored bf16
  int lane = threadIdx.x & 63;
  int node = (blockIdx.x * blockDim.x + threadIdx.x) >> 6;
  if (node >= Nn) return;
  int s = (node == 0) ? 0 : rowptr[node - 1];
  int e = rowptr[node];
  int half = lane >> 5;                 // which edge of the pair
  int hl = lane & 31;                   // pair index within row (feature f=2*hl)
  int f = hl * 2;
  const unsigned* yu = (const unsigned*)y;    // row = 32 bf16-pairs
  float p0a = 0, p1a = 0, p0b = 0, p1b = 0;
  float p0c = 0, p1c = 0, p0d = 0, p1d = 0;
  for (int base = s; base < e; base += 64) {
    int cnt = e - base; if (cnt > 64) cnt = 64;
    int rl = (base + lane < e) ? csr[base + lane] : 0;
    int j = 0;
    for (; j + 8 <= cnt; j += 8) {
      int r0 = __shfl(rl, j + half, 64);
      int r1 = __shfl(rl, j + 2 + half, 64);
      int r2 = __shfl(rl, j + 4 + half, 64);
      int r3 = __shfl(rl, j + 6 + half, 64);
      unsigned u0 = yu[(unsigned)r0 * 32u + hl];
      unsigned u1 = yu[(unsigned)r1 * 32u + hl];
      unsigned u2 = yu[(unsigned)r2 * 32u + hl];
      unsigned u3 = yu[(unsigned)r3 * 32u + hl];
      p0a += blo(u0); p1a += bhi(u0);
      p0b += blo(u1); p1b += bhi(u1);
      p0c += blo(u2); p1c += bhi(u2);
      p0d += blo(u3); p1d += bhi(u3);
    }
    for (; j + 2 <= cnt; j += 2) {
      int r0 = __shfl(rl, j + half, 64);
      unsigned u0 = yu[(unsigned)r0 * 32u + hl];
      p0a += blo(u0); p1a += bhi(u0);
    }
    if (j < cnt) {                      // odd tail: half 0 only
      int r0 = __shfl(rl, j, 64);
      if (half == 0) {
        unsigned u0 = yu[(unsigned)r0 * 32u + hl];
        p0a += blo(u0); p1a += bhi(u0);
      }
    }
  }
  float acc0 = (p0a + p0b) + (p0c + p0d);
  float acc1 = (p1a + p1b) + (p1c + p1d);
  acc0 += __shfl_xor(acc0, 32, 64);     // combine the two edge-halves
  acc1 += __shfl_xor(acc1, 32, 64);
  unsigned un = yu[(unsigned)node * 32u + hl];   // self term: y[node]*di
  acc0 += blo(un); acc1 += bhi(un);
  float di = dinv[node];
  float v0 = lk(di * acc0 + loadF(bias, (size_t)f, f32));
  float v1 = lk(di * acc1 + loadF(bias, (size_t)(f + 1), f32));
  if (half == 0) {
    if (of32) {
      *(float2*)((float*)outp + obase + (size_t)node * 64 + f) = make_float2(v0, v1);
    } else {
      union { unsigned u; unsigned short s[2]; } pk;
      pk.s[0] = (unsigned short)f2b(v0);
      pk.s[1] = (unsigned short)f2b(v1);
      *(unsigned*)((__hip_bfloat16*)outp + obase + (size_t)node * 64 + f) = pk.u;
    }
  }
  if (ssrc) {
    float q1 = v0 * loadF(Wp, (size_t)f, f32) + v1 * loadF(Wp, (size_t)(f + 1), f32);
    float q2 = v0 * loadF(Wp, (size_t)(64 + f), f32) + v1 * loadF(Wp, (size_t)(65 + f), f32);
#pragma unroll
    for (int o = 16; o > 0; o >>= 1) {
      q1 += __shfl_down(q1, o, 64);
      q2 += __shfl_down(q2, o, 64);
    }
    if (lane == 0) { ssrc[node] = q1; sdst[node] = q2; }
  }
}

// ---- edge scoring head: one THREAD per edge, scores precomputed -------------
__global__ __launch_bounds__(256) void edge_head_kernel(void* __restrict__ dout,
                                                        const int* __restrict__ eli,
                                                        const void* __restrict__ ea,
                                                        const float* __restrict__ ssrc,
                                                        const float* __restrict__ sdst,
                                                        const void* __restrict__ Wp,
                                                        const void* __restrict__ bp,
                                                        int EL, const int* __restrict__ flags) {
  int f32 = flags[0] != 0;
  int i64 = flags[1] == 0;
  int tid = blockIdx.x * blockDim.x + threadIdx.x;
  if (tid >= EL) return;
  int s = loadI(eli, 0, (size_t)tid, i64);
  int d = loadI(eli, (size_t)EL, (size_t)tid, i64);
  float acc = ssrc[s] + sdst[d] + loadF(bp, 0, f32);
  if (f32) {
    const float* eap = (const float*)ea + (size_t)tid * 8;
    float4 u0 = *(const float4*)eap;
    float4 u1 = *(const float4*)(eap + 4);
    acc += u0.x * loadF(Wp, 128, 1) + u0.y * loadF(Wp, 129, 1) +
           u0.z * loadF(Wp, 130, 1) + u0.w * loadF(Wp, 131, 1) +
           u1.x * loadF(Wp, 132, 1) + u1.y * loadF(Wp, 133, 1) +
           u1.z * loadF(Wp, 134, 1) + u1.w * loadF(Wp, 135, 1);
  } else {
    bf16x8 u = *(const bf16x8*)((const __hip_bfloat16*)ea + (size_t)tid * 8);
#pragma unroll
    for (int j = 0; j < 8; ++j) {
      union { short s; __hip_bfloat16 h; } cv; cv.s = u[j];
      acc += __bfloat162float(cv.h) * loadF(Wp, (size_t)(128 + j), 0);
    }
  }
  storeF(dout, (size_t)tid, f32, acc);
}

extern "C" void kernel_launch(void* const* d_in, const int* in_sizes, int n_in,
                              void* d_out, int out_size, void* d_ws, size_t ws_size,
                              hipStream_t stream) {
  const void* x   = d_in[0];
  const int* ei   = (const int*)d_in[1];
  const int* eli  = (const int*)d_in[2];
  const void* ea  = d_in[3];
  const void* W1  = d_in[4];
  const void* b1  = d_in[5];
  const void* W2  = d_in[6];
  const void* b2  = d_in[7];
  const void* Wg1 = d_in[8];
  const void* bg1 = d_in[9];
  const void* Wg2 = d_in[10];
  const void* bg2 = d_in[11];
  const void* Wp  = d_in[12];
  const void* bp  = d_in[13];

  const int Nn = in_sizes[0] / 256;
  const int E  = in_sizes[1] / 2;
  const int EL = in_sizes[2] / 2;
  const int NB = (Nn + BW - 1) >> BSHIFT;       // col buckets

  char* ws = (char*)d_ws;
  size_t off = 0;
  auto take = [&](size_t bytes) -> char* {
    char* p = ws + off;
    off = (off + bytes + 255) & ~(size_t)255;
    return p;
  };
  int*   flags  = (int*)take(256);
  int*   cur    = (int*)take((size_t)NB * NSTR * 4);   // contiguous after flags
  int*   bbase  = (int*)take((size_t)NB * 4);
  int*   rowptr = (int*)take((size_t)Nn * 4);
  float* dinv   = (float*)take((size_t)Nn * 4);
  float* ssrc   = (float*)take((size_t)Nn * 4);
  float* sdst   = (float*)take((size_t)Nn * 4);
  int*   csr    = (int*)take((size_t)E * 4);
  int2*  rec    = (int2*)take((size_t)NB * NSTR * BCAP * 8);
  __hip_bfloat16* pW1 = (__hip_bfloat16*)take(256 * 128 * 2);
  __hip_bfloat16* pW2 = (__hip_bfloat16*)take(128 * 64 * 2);
  __hip_bfloat16* pG1 = (__hip_bfloat16*)take(64 * 64 * 2);
  __hip_bfloat16* pG2 = (__hip_bfloat16*)take(64 * 64 * 2);
  char* regionA = take((size_t)Nn * 128 * 4);   // h1(bf16) | y(bf16) at +Nn*256B
  char* regionB = take((size_t)Nn * 64 * 4);    // h2(bf16) | later h3(bf16)
  __hip_bfloat16* h1 = (__hip_bfloat16*)regionA;
  __hip_bfloat16* y = (__hip_bfloat16*)(regionA + (size_t)Nn * 64 * 4);
  __hip_bfloat16* h2 = (__hip_bfloat16*)regionB;
  __hip_bfloat16* h3 = (__hip_bfloat16*)regionB;

  // flags + cur are contiguous -> one memset covers both
  hipMemsetAsync(flags, 0, 256 + (((size_t)NB * NSTR * 4 + 255) & ~(size_t)255), stream);
  detect_kernel<<<1, 256, 0, stream>>>((const unsigned short*)x, ei, flags);

  dim3 b64(64);
  pack_w_kernel<<<dim3(8, 8), b64, 0, stream>>>(W1, pW1, 128, flags);
  pack_w_kernel<<<dim3(4, 4), b64, 0, stream>>>(W2, pW2, 64, flags);
  pack_w_kernel<<<dim3(2, 4), b64, 0, stream>>>(Wg1, pG1, 64, flags);
  pack_w_kernel<<<dim3(2, 4), b64, 0, stream>>>(Wg2, pG2, 64, flags);

  // CSR build: LDS-staged binning -> scan -> place
  const int ldsbytes = NB * (8 + LCAP * 8);     // bcnt + gbase + bins
  const int nbin = (E + 256 * KEDGE - 1) / (256 * KEDGE);
  bin_kernel<<<nbin, 256, ldsbytes, stream>>>(ei, cur, rec, E, NB, flags);
  bucket_scan<<<1, 512, 0, stream>>>(cur, bbase, NB);
  place_kernel<<<NB, 256, 0, stream>>>(rec, cur, bbase, rowptr, csr, dinv, Nn);

  // tiled GEMMs: block = 32 rows, 4 waves = 4 col-partitions
  const int tblocks = (Nn + 31) / 32;
  gemm_tiled<8, 2, 1><<<tblocks, 256, 0, stream>>>(x, pW1, b1, h1, 1, nullptr, nullptr,
                                                   Nn, 128, 1, flags);
  gemm_tiled<4, 1, 0><<<tblocks, 256, 0, stream>>>(h1, pW2, b2, h2, 1, nullptr, nullptr,
                                                   Nn, 64, 1, flags);

  gemm_tiled<2, 1, 0><<<tblocks, 256, 0, stream>>>(h2, pG1, nullptr, nullptr, 0, y, dinv,
                                                   Nn, 64, 0, flags);
  gather_kernel<<<(Nn + 3) / 4, 256, 0, stream>>>(y, csr, rowptr, dinv, bg1,
                                                  h3, 0, 0, Nn,
                                                  nullptr, nullptr, nullptr, flags);

  gemm_tiled<2, 1, 0><<<tblocks, 256, 0, stream>>>(h3, pG2, nullptr, nullptr, 0, y, dinv,
                                                   Nn, 64, 0, flags);
  gather_kernel<<<(Nn + 3) / 4, 256, 0, stream>>>(y, csr, rowptr, dinv, bg2,
                                                  d_out, (size_t)EL, 1, Nn,
                                                  ssrc, sdst, Wp, flags);

  edge_head_kernel<<<(EL + 255) / 256, 256, 0, stream>>>(d_out, eli, ea, ssrc, sdst,
                                                         Wp, bp, EL, flags);
}

// Round 5
// 392.147 us; speedup vs baseline: 1.3170x; 1.0646x over previous
//
#include <hip/hip_runtime.h>
#include <hip/hip_bf16.h>

typedef __attribute__((ext_vector_type(8))) short bf16x8;
typedef __attribute__((ext_vector_type(4))) float f32x4;

#define BSHIFT 8          // cols per bucket = 256
#define BW 256
#define NSTR 8            // stripes (XCDs)
#define BCAP 768          // records per (bucket,stripe) stream; mean ~511
#define LCAP 24           // LDS records per bucket per round
#define KEDGE 16          // edges per thread per round (4096/block-round)

__device__ __forceinline__ float lk(float v) { return v > 0.f ? v : 0.01f * v; }

__device__ __forceinline__ short f2b(float v) {
  union { __hip_bfloat16 h; short s; } u;
  u.h = __float2bfloat16(v);
  return u.s;
}
__device__ __forceinline__ float loadF(const void* p, size_t i, int f32) {
  return f32 ? ((const float*)p)[i]
             : __bfloat162float(((const __hip_bfloat16*)p)[i]);
}
__device__ __forceinline__ void storeF(void* p, size_t i, int f32, float v) {
  if (f32) ((float*)p)[i] = v;
  else     ((__hip_bfloat16*)p)[i] = __float2bfloat16(v);
}
__device__ __forceinline__ int loadI(const int* p, size_t base, size_t e, int i64) {
  return i64 ? p[2 * (base + e)] : p[base + e];
}
// bf16 pair (u32) -> two floats via bit ops (no cvt instruction)
__device__ __forceinline__ float blo(unsigned u) {
  union { unsigned u; float f; } c; c.u = u << 16; return c.f;
}
__device__ __forceinline__ float bhi(unsigned u) {
  union { unsigned u; float f; } c; c.u = u & 0xffff0000u; return c.f;
}

// ---- dtype detection (device-side, graph-safe) ------------------------------
__global__ void detect_kernel(const unsigned short* __restrict__ x,
                              const int* __restrict__ ei, int* __restrict__ flags) {
  int t = threadIdx.x;
  unsigned short u = x[t];
  int ex = (u >> 7) & 0xFF;
  if (ex >= 0xC0) atomicOr(&flags[0], 1);          // fp32 viewed as bf16 -> wild exps
  if (t < 128 && ei[2 * t + 1] != 0) atomicOr(&flags[1], 1);  // nonzero -> int32
}

// ---- pack W [K,N] row-major -> MFMA B-fragment layout (bf16) ----------------
__global__ __launch_bounds__(64) void pack_w_kernel(const void* __restrict__ W,
                                                    __hip_bfloat16* __restrict__ P,
                                                    int N, const int* __restrict__ flags) {
  int f32 = flags[0] != 0;
  int ks = blockIdx.x, ct = blockIdx.y, KS = gridDim.x;
  int lane = threadIdx.x;
  int g = lane >> 4, m = lane & 15;
  size_t base = ((size_t)(ct * KS + ks) * 64 + (size_t)lane) * 8;
#pragma unroll
  for (int j = 0; j < 8; ++j)
    P[base + j] = __float2bfloat16(
        loadF(W, (size_t)(ks * 32 + g * 8 + j) * N + (size_t)(ct * 16 + m), f32));
}

// ---- tiled GEMM with global_load_lds A-staging ------------------------------
// Block = 4 waves, tile = 32 rows x K. Wave w owns col-partition w (CT tiles).
// LDS dest is linear; global SOURCE is pre-swizzled with the same XOR the
// ds reads use (rule 21: both-sides-or-neither).
//   f32  A: frag = 32B = chunk pair (c,c+1), xor = (row&3)<<1 (keeps pairs)
//   bf16 A: frag = 16B = 1 chunk,            xor = (row&7)

template <int ROWB, int F32>
__device__ __forceinline__ void stage_tile(const char* __restrict__ Ab, char* tile,
                                           int row0, int M, int w, int lane) {
  constexpr int CPR = ROWB / 16;     // 16B chunks per row
  constexpr int PERW = 32 * CPR / 4; // chunks per wave (multiple of 64)
#pragma unroll
  for (int i = 0; i < PERW; i += 64) {
    int p = w * PERW + i + lane;
    int r = p / CPR;
    int pc = p - r * CPR;
    int xv = F32 ? ((r & 3) << 1) : (r & 7);
    int gr = row0 + r; if (gr >= M) gr = M - 1;
    const char* src = Ab + (size_t)gr * ROWB + (size_t)(pc ^ xv) * 16;
    char* dst = tile + (size_t)(w * PERW + i) * 16;   // wave-uniform base
    __builtin_amdgcn_global_load_lds(
        (const __attribute__((address_space(1))) void*)src,
        (__attribute__((address_space(3))) void*)dst, 16, 0, 0);
  }
}

template <int KS, int CT, int F32>
__device__ __forceinline__ void tile_core(const char* tile,
                                          const __hip_bfloat16* __restrict__ bbase,
                                          int m, int g, f32x4 (&accs)[2][CT]) {
  constexpr int ROWB = KS * 32 * (F32 ? 4 : 2);
#pragma unroll
  for (int ks = 0; ks < KS; ++ks) {
    bf16x8 a[2];
#pragma unroll
    for (int t = 0; t < 2; ++t) {
      int r = t * 16 + m;
      if constexpr (F32) {
        int c = ks * 8 + g * 2;                 // chunk pair c, c+1
        int xv = (r & 3) << 1;
        float4 q0 = *(const float4*)(tile + (size_t)r * ROWB + (size_t)((c ^ xv) * 16));
        float4 q1 = *(const float4*)(tile + (size_t)r * ROWB + (size_t)(((c + 1) ^ xv) * 16));
        a[t][0] = f2b(q0.x); a[t][1] = f2b(q0.y); a[t][2] = f2b(q0.z); a[t][3] = f2b(q0.w);
        a[t][4] = f2b(q1.x); a[t][5] = f2b(q1.y); a[t][6] = f2b(q1.z); a[t][7] = f2b(q1.w);
      } else {
        int c = ks * 4 + g;                     // single 16B chunk
        int xv = r & 7;
        a[t] = *(const bf16x8*)(tile + (size_t)r * ROWB + (size_t)((c ^ xv) * 16));
      }
    }
    const __hip_bfloat16* bb = bbase + (size_t)ks * 64 * 8;
#pragma unroll
    for (int cc = 0; cc < CT; ++cc) {
      bf16x8 b = *(const bf16x8*)(bb + (size_t)cc * KS * 64 * 8);
#pragma unroll
      for (int t = 0; t < 2; ++t)
        accs[t][cc] = __builtin_amdgcn_mfma_f32_16x16x32_bf16(a[t], b, accs[t][cc], 0, 0, 0);
    }
  }
}

// AMODE: 0 = A always bf16; 1 = A dtype from flags[0] (fp32 or bf16)
// Out may be nullptr (write only Yout = bf16(v * dinv[row]))
template <int KS, int CT, int AMODE>
__global__ __launch_bounds__(256) void gemm_tiled(const void* __restrict__ A,
                                                  const __hip_bfloat16* __restrict__ Bp,
                                                  const void* __restrict__ bias,
                                                  void* __restrict__ Out, int out_bf16,
                                                  __hip_bfloat16* __restrict__ Yout,
                                                  const float* __restrict__ dinv,
                                                  int M, int N, int act,
                                                  const int* __restrict__ flags) {
  constexpr int K = KS * 32;
  constexpr int LDSB = 32 * K * (AMODE ? 4 : 2);
  __shared__ char tile[LDSB];
  int f32 = AMODE ? (flags[0] != 0) : 0;
  int lane = threadIdx.x & 63;
  int w = threadIdx.x >> 6;                     // wave id = col partition
  int m = lane & 15, g = lane >> 4;
  int row0 = blockIdx.x * 32;

  const char* Ab = (const char*)A;
  if (f32) stage_tile<K * 4, 1>(Ab, tile, row0, M, w, lane);
  else     stage_tile<K * 2, 0>(Ab, tile, row0, M, w, lane);
  __syncthreads();

  const __hip_bfloat16* bbase = Bp + ((size_t)(w * CT) * KS * 64 + (size_t)lane) * 8;
  f32x4 accs[2][CT];
#pragma unroll
  for (int t = 0; t < 2; ++t)
#pragma unroll
    for (int cc = 0; cc < CT; ++cc) accs[t][cc] = (f32x4){0, 0, 0, 0};

  if (f32) tile_core<KS, CT, 1>(tile, bbase, m, g, accs);
  else     tile_core<KS, CT, 0>(tile, bbase, m, g, accs);

  // epilogue
  float bv[CT];
#pragma unroll
  for (int cc = 0; cc < CT; ++cc)
    bv[cc] = bias ? loadF(bias, (size_t)((w * CT + cc) * 16 + m), flags[0] != 0) : 0.f;
#pragma unroll
  for (int t = 0; t < 2; ++t) {
#pragma unroll
    for (int r = 0; r < 4; ++r) {
      int ro = row0 + t * 16 + g * 4 + r;
      if (ro < M) {
        float di = Yout ? dinv[ro] : 0.f;
#pragma unroll
        for (int cc = 0; cc < CT; ++cc) {
          int col = (w * CT + cc) * 16 + m;
          float v = accs[t][cc][r] + bv[cc];
          if (act) v = lk(v);
          if (Out) {
            if (out_bf16) ((__hip_bfloat16*)Out)[(size_t)ro * N + col] = __float2bfloat16(v);
            else          ((float*)Out)[(size_t)ro * N + col] = v;
          }
          if (Yout) Yout[(size_t)ro * N + col] = __float2bfloat16(v * di);
        }
      }
    }
  }
}

// ---- CSR build pass A: LDS-staged binning, batched stream flush -------------
// LDS: bcnt[NB] | gbase[NB] | bins[NB*LCAP] (int2)
__global__ __launch_bounds__(256) void bin_kernel(const int* __restrict__ ei,
                                                  int* __restrict__ cur,
                                                  int2* __restrict__ rec,
                                                  int E, int NB,
                                                  const int* __restrict__ flags) {
  extern __shared__ int lds[];
  int* bcnt = lds;
  int* gbase = lds + NB;
  int2* bins = (int2*)(lds + 2 * NB);
  int i64 = flags[1] == 0;
  // real XCD id (hwreg 20); any value is correctness-safe after &7
  int stripe = __builtin_amdgcn_s_getreg(63508) & (NSTR - 1);
  int t = threadIdx.x;
  const int perRound = 256 * KEDGE;
  for (int base = blockIdx.x * perRound; base < E; base += gridDim.x * perRound) {
    for (int b = t; b < NB; b += 256) bcnt[b] = 0;
    __syncthreads();
    // bin into LDS
#pragma unroll 1
    for (int k = 0; k < KEDGE; ++k) {
      int i = base + k * 256 + t;
      if (i < E) {
        int r, c;
        if (i64) {
          r = ((const int2*)ei)[i].x;            // int64 low word
          c = ((const int2*)ei)[(size_t)E + i].x;
        } else {
          r = ei[i];
          c = ei[(size_t)E + i];
        }
        int b = c >> BSHIFT;
        int pos = atomicAdd(&bcnt[b], 1);
        if (pos < LCAP) {
          bins[b * LCAP + pos] = make_int2(r, c);
        } else {                                   // rare overflow: direct append
          int bs = b * NSTR + stripe;
          int slot = atomicAdd(&cur[bs], 1);
          if (slot < BCAP) rec[(size_t)bs * BCAP + slot] = make_int2(r, c);
        }
      }
    }
    __syncthreads();
    // reserve stream ranges (parallel atomics, no serialized chain)
    for (int b = t; b < NB; b += 256) {
      int n = min(bcnt[b], LCAP);
      if (n > 0) gbase[b] = atomicAdd(&cur[b * NSTR + stripe], n);
    }
    __syncthreads();
    // contiguous copy LDS -> stream
    int lane = t & 63, w = t >> 6;
    for (int b = w; b < NB; b += 4) {
      int n = min(bcnt[b], LCAP);
      if (n == 0) continue;
      int gb = gbase[b];
      size_t sb = (size_t)(b * NSTR + stripe) * BCAP;
      if (lane < n && gb + lane < BCAP)
        rec[sb + gb + lane] = bins[b * LCAP + lane];
    }
    __syncthreads();
  }
}

// exclusive prefix over bucket totals (single block; NB <= 512)
__global__ __launch_bounds__(512) void bucket_scan(const int* __restrict__ cur,
                                                   int* __restrict__ bbase, int NB) {
  __shared__ int lds[512];
  int t = threadIdx.x;
  int tot = 0;
  if (t < NB)
#pragma unroll
    for (int s = 0; s < NSTR; ++s) tot += min(cur[t * NSTR + s], BCAP);
  lds[t] = tot; __syncthreads();
  for (int o = 1; o < 512; o <<= 1) {
    int a = (t >= o) ? lds[t - o] : 0; __syncthreads();
    lds[t] += a; __syncthreads();
  }
  if (t < NB) bbase[t] = lds[t] - tot;
}

// Pass B: one block per bucket, 512 threads (place was grid-starved at 256).
// LDS count -> scan (first 256 lanes) -> rowptr/dinv -> place
__global__ __launch_bounds__(512) void place_kernel(const int2* __restrict__ rec,
                                                    const int* __restrict__ cur,
                                                    const int* __restrict__ bbase,
                                                    int* __restrict__ rowptr,
                                                    int* __restrict__ csr,
                                                    float* __restrict__ dinv, int Nn) {
  int b = blockIdx.x;
  int lo = b << BSHIFT;
  int t = threadIdx.x;
  __shared__ int cnt[BW];
  __shared__ int sc[BW];
  __shared__ int cursor[BW];
  if (t < BW) cnt[t] = 0;
  __syncthreads();
#pragma unroll 1
  for (int s = 0; s < NSTR; ++s) {
    int n = min(cur[b * NSTR + s], BCAP);
    const int2* rp = rec + (size_t)(b * NSTR + s) * BCAP;
    for (int j = t; j < n; j += 512) atomicAdd(&cnt[rp[j].y - lo], 1);
  }
  __syncthreads();
  int v = 0;
  if (t < BW) { v = cnt[t]; sc[t] = v; }
  __syncthreads();
  for (int o = 1; o < BW; o <<= 1) {
    int a = (t >= o && t < BW) ? sc[t - o] : 0;
    __syncthreads();
    if (t < BW) sc[t] += a;
    __syncthreads();
  }
  if (t < BW) {
    int base = bbase[b];
    int col = lo + t;
    if (col < Nn) {
      rowptr[col] = base + sc[t];               // segment END
      dinv[col] = rsqrtf((float)v + 1.0f);
    }
    cursor[t] = base + sc[t] - v;               // segment start
  }
  __syncthreads();
#pragma unroll 1
  for (int s = 0; s < NSTR; ++s) {
    int n = min(cur[b * NSTR + s], BCAP);
    const int2* rp = rec + (size_t)(b * NSTR + s) * BCAP;
    for (int j = t; j < n; j += 512) {
      int2 e = rp[j];
      int pos = atomicAdd(&cursor[e.y - lo], 1);
      csr[pos] = e.x;
    }
  }
}

// ---- pull-mode aggregation + self-term + bias + leaky, fused ----------------
// Half-wave (32 lanes) per node: halves per-node wave overhead, doubles edge
// loads in flight. Each lane covers a bf16 feature-pair (u32). Self term uses
// y[node]*di == xw*di*di (extra bf16 rounding scaled by 1/(deg+1): negligible).
// Optionally reduces edge-head scores ssrc[n]=h[n].wp1, sdst[n]=h[n].wp2.
__global__ __launch_bounds__(256) void gather_kernel(const __hip_bfloat16* __restrict__ y,
                                                     const int* __restrict__ csr,
                                                     const int* __restrict__ rowptr,
                                                     const float* __restrict__ dinv,
                                                     const void* __restrict__ bias,
                                                     void* __restrict__ outp, size_t obase,
                                                     int out_use_flag, int Nn,
                                                     float* __restrict__ ssrc,
                                                     float* __restrict__ sdst,
                                                     const void* __restrict__ Wp,
                                                     const int* __restrict__ flags) {
  int f32 = flags[0] != 0;
  int of32 = out_use_flag ? f32 : 0;    // intermediate h3 stored bf16
  int lane = threadIdx.x & 63;
  int w = (blockIdx.x * blockDim.x + threadIdx.x) >> 6;
  if (2 * w >= Nn) return;
  int half = lane >> 5;                 // which node of the pair
  int hl = lane & 31;                   // feature-pair index (f = 2*hl)
  int hb = half << 5;                   // shfl base for this half
  int node = 2 * w + half;
  int alive = node < Nn;
  int nd = alive ? node : Nn - 1;       // clamp for safe loads
  int s = (nd == 0) ? 0 : rowptr[nd - 1];
  int e = rowptr[nd];
  if (!alive) e = s;
  const unsigned* yu = (const unsigned*)y;    // row = 32 bf16-pairs
  float p0a = 0, p1a = 0, p0b = 0, p1b = 0;
  float p0c = 0, p1c = 0, p0d = 0, p1d = 0;
  for (int base = s; base < e; base += 32) {
    int cnt = e - base; if (cnt > 32) cnt = 32;
    int rl = (base + hl < e) ? csr[base + hl] : 0;
    int j = 0;
    for (; j + 8 <= cnt; j += 8) {
      int r0 = __shfl(rl, hb + j + 0, 64);
      int r1 = __shfl(rl, hb + j + 1, 64);
      int r2 = __shfl(rl, hb + j + 2, 64);
      int r3 = __shfl(rl, hb + j + 3, 64);
      int r4 = __shfl(rl, hb + j + 4, 64);
      int r5 = __shfl(rl, hb + j + 5, 64);
      int r6 = __shfl(rl, hb + j + 6, 64);
      int r7 = __shfl(rl, hb + j + 7, 64);
      unsigned u0 = yu[(unsigned)r0 * 32u + hl];
      unsigned u1 = yu[(unsigned)r1 * 32u + hl];
      unsigned u2 = yu[(unsigned)r2 * 32u + hl];
      unsigned u3 = yu[(unsigned)r3 * 32u + hl];
      unsigned u4 = yu[(unsigned)r4 * 32u + hl];
      unsigned u5 = yu[(unsigned)r5 * 32u + hl];
      unsigned u6 = yu[(unsigned)r6 * 32u + hl];
      unsigned u7 = yu[(unsigned)r7 * 32u + hl];
      p0a += blo(u0); p1a += bhi(u0);
      p0b += blo(u1); p1b += bhi(u1);
      p0c += blo(u2); p1c += bhi(u2);
      p0d += blo(u3); p1d += bhi(u3);
      p0a += blo(u4); p1a += bhi(u4);
      p0b += blo(u5); p1b += bhi(u5);
      p0c += blo(u6); p1c += bhi(u6);
      p0d += blo(u7); p1d += bhi(u7);
    }
    for (; j + 4 <= cnt; j += 4) {
      int r0 = __shfl(rl, hb + j + 0, 64);
      int r1 = __shfl(rl, hb + j + 1, 64);
      int r2 = __shfl(rl, hb + j + 2, 64);
      int r3 = __shfl(rl, hb + j + 3, 64);
      unsigned u0 = yu[(unsigned)r0 * 32u + hl];
      unsigned u1 = yu[(unsigned)r1 * 32u + hl];
      unsigned u2 = yu[(unsigned)r2 * 32u + hl];
      unsigned u3 = yu[(unsigned)r3 * 32u + hl];
      p0a += blo(u0); p1a += bhi(u0);
      p0b += blo(u1); p1b += bhi(u1);
      p0c += blo(u2); p1c += bhi(u2);
      p0d += blo(u3); p1d += bhi(u3);
    }
    for (; j < cnt; ++j) {
      int r0 = __shfl(rl, hb + j, 64);
      unsigned u0 = yu[(unsigned)r0 * 32u + hl];
      p0a += blo(u0); p1a += bhi(u0);
    }
  }
  float acc0 = (p0a + p0b) + (p0c + p0d);
  float acc1 = (p1a + p1b) + (p1c + p1d);
  unsigned un = yu[(unsigned)nd * 32u + hl];   // self term: y[node]*di
  acc0 += blo(un); acc1 += bhi(un);
  float di = dinv[nd];
  int f = hl * 2;
  float v0 = lk(di * acc0 + loadF(bias, (size_t)f, f32));
  float v1 = lk(di * acc1 + loadF(bias, (size_t)(f + 1), f32));
  if (alive) {
    if (of32) {
      *(float2*)((float*)outp + obase + (size_t)node * 64 + f) = make_float2(v0, v1);
    } else {
      union { unsigned u; unsigned short ss[2]; } pk;
      pk.ss[0] = (unsigned short)f2b(v0);
      pk.ss[1] = (unsigned short)f2b(v1);
      *(unsigned*)((__hip_bfloat16*)outp + obase + (size_t)node * 64 + f) = pk.u;
    }
  }
  if (ssrc) {
    float q1 = v0 * loadF(Wp, (size_t)f, f32) + v1 * loadF(Wp, (size_t)(f + 1), f32);
    float q2 = v0 * loadF(Wp, (size_t)(64 + f), f32) + v1 * loadF(Wp, (size_t)(65 + f), f32);
#pragma unroll
    for (int o = 16; o > 0; o >>= 1) {        // reduce within each 32-lane half
      q1 += __shfl_down(q1, o, 64);
      q2 += __shfl_down(q2, o, 64);
    }
    if (hl == 0 && alive) { ssrc[node] = q1; sdst[node] = q2; }
  }
}

// ---- edge scoring head: one THREAD per edge, scores precomputed -------------
__global__ __launch_bounds__(256) void edge_head_kernel(void* __restrict__ dout,
                                                        const int* __restrict__ eli,
                                                        const void* __restrict__ ea,
                                                        const float* __restrict__ ssrc,
                                                        const float* __restrict__ sdst,
                                                        const void* __restrict__ Wp,
                                                        const void* __restrict__ bp,
                                                        int EL, const int* __restrict__ flags) {
  int f32 = flags[0] != 0;
  int i64 = flags[1] == 0;
  int tid = blockIdx.x * blockDim.x + threadIdx.x;
  if (tid >= EL) return;
  int s = loadI(eli, 0, (size_t)tid, i64);
  int d = loadI(eli, (size_t)EL, (size_t)tid, i64);
  float acc = ssrc[s] + sdst[d] + loadF(bp, 0, f32);
  if (f32) {
    const float* eap = (const float*)ea + (size_t)tid * 8;
    float4 u0 = *(const float4*)eap;
    float4 u1 = *(const float4*)(eap + 4);
    acc += u0.x * loadF(Wp, 128, 1) + u0.y * loadF(Wp, 129, 1) +
           u0.z * loadF(Wp, 130, 1) + u0.w * loadF(Wp, 131, 1) +
           u1.x * loadF(Wp, 132, 1) + u1.y * loadF(Wp, 133, 1) +
           u1.z * loadF(Wp, 134, 1) + u1.w * loadF(Wp, 135, 1);
  } else {
    bf16x8 u = *(const bf16x8*)((const __hip_bfloat16*)ea + (size_t)tid * 8);
#pragma unroll
    for (int j = 0; j < 8; ++j) {
      union { short s; __hip_bfloat16 h; } cv; cv.s = u[j];
      acc += __bfloat162float(cv.h) * loadF(Wp, (size_t)(128 + j), 0);
    }
  }
  storeF(dout, (size_t)tid, f32, acc);
}

extern "C" void kernel_launch(void* const* d_in, const int* in_sizes, int n_in,
                              void* d_out, int out_size, void* d_ws, size_t ws_size,
                              hipStream_t stream) {
  const void* x   = d_in[0];
  const int* ei   = (const int*)d_in[1];
  const int* eli  = (const int*)d_in[2];
  const void* ea  = d_in[3];
  const void* W1  = d_in[4];
  const void* b1  = d_in[5];
  const void* W2  = d_in[6];
  const void* b2  = d_in[7];
  const void* Wg1 = d_in[8];
  const void* bg1 = d_in[9];
  const void* Wg2 = d_in[10];
  const void* bg2 = d_in[11];
  const void* Wp  = d_in[12];
  const void* bp  = d_in[13];

  const int Nn = in_sizes[0] / 256;
  const int E  = in_sizes[1] / 2;
  const int EL = in_sizes[2] / 2;
  const int NB = (Nn + BW - 1) >> BSHIFT;       // col buckets

  char* ws = (char*)d_ws;
  size_t off = 0;
  auto take = [&](size_t bytes) -> char* {
    char* p = ws + off;
    off = (off + bytes + 255) & ~(size_t)255;
    return p;
  };
  int*   flags  = (int*)take(256);
  int*   cur    = (int*)take((size_t)NB * NSTR * 4);   // contiguous after flags
  int*   bbase  = (int*)take((size_t)NB * 4);
  int*   rowptr = (int*)take((size_t)Nn * 4);
  float* dinv   = (float*)take((size_t)Nn * 4);
  float* ssrc   = (float*)take((size_t)Nn * 4);
  float* sdst   = (float*)take((size_t)Nn * 4);
  int*   csr    = (int*)take((size_t)E * 4);
  int2*  rec    = (int2*)take((size_t)NB * NSTR * BCAP * 8);
  __hip_bfloat16* pW1 = (__hip_bfloat16*)take(256 * 128 * 2);
  __hip_bfloat16* pW2 = (__hip_bfloat16*)take(128 * 64 * 2);
  __hip_bfloat16* pG1 = (__hip_bfloat16*)take(64 * 64 * 2);
  __hip_bfloat16* pG2 = (__hip_bfloat16*)take(64 * 64 * 2);
  char* regionA = take((size_t)Nn * 128 * 4);   // h1(bf16) | y(bf16) at +Nn*256B
  char* regionB = take((size_t)Nn * 64 * 4);    // h2(bf16) | later h3(bf16)
  __hip_bfloat16* h1 = (__hip_bfloat16*)regionA;
  __hip_bfloat16* y = (__hip_bfloat16*)(regionA + (size_t)Nn * 64 * 4);
  __hip_bfloat16* h2 = (__hip_bfloat16*)regionB;
  __hip_bfloat16* h3 = (__hip_bfloat16*)regionB;

  // flags + cur are contiguous -> one memset covers both
  hipMemsetAsync(flags, 0, 256 + (((size_t)NB * NSTR * 4 + 255) & ~(size_t)255), stream);
  detect_kernel<<<1, 256, 0, stream>>>((const unsigned short*)x, ei, flags);

  dim3 b64(64);
  pack_w_kernel<<<dim3(8, 8), b64, 0, stream>>>(W1, pW1, 128, flags);
  pack_w_kernel<<<dim3(4, 4), b64, 0, stream>>>(W2, pW2, 64, flags);
  pack_w_kernel<<<dim3(2, 4), b64, 0, stream>>>(Wg1, pG1, 64, flags);
  pack_w_kernel<<<dim3(2, 4), b64, 0, stream>>>(Wg2, pG2, 64, flags);

  // CSR build: LDS-staged binning -> scan -> place
  const int ldsbytes = NB * (8 + LCAP * 8);     // bcnt + gbase + bins
  const int nbin = (E + 256 * KEDGE - 1) / (256 * KEDGE);
  bin_kernel<<<nbin, 256, ldsbytes, stream>>>(ei, cur, rec, E, NB, flags);
  bucket_scan<<<1, 512, 0, stream>>>(cur, bbase, NB);
  place_kernel<<<NB, 512, 0, stream>>>(rec, cur, bbase, rowptr, csr, dinv, Nn);

  // tiled GEMMs: block = 32 rows, 4 waves = 4 col-partitions
  const int tblocks = (Nn + 31) / 32;
  gemm_tiled<8, 2, 1><<<tblocks, 256, 0, stream>>>(x, pW1, b1, h1, 1, nullptr, nullptr,
                                                   Nn, 128, 1, flags);
  gemm_tiled<4, 1, 0><<<tblocks, 256, 0, stream>>>(h1, pW2, b2, h2, 1, nullptr, nullptr,
                                                   Nn, 64, 1, flags);

  // gathers: 2 nodes per wave (half-wave per node)
  const int gwaves = (Nn + 1) / 2;
  const int gblocks = (gwaves + 3) / 4;
  gemm_tiled<2, 1, 0><<<tblocks, 256, 0, stream>>>(h2, pG1, nullptr, nullptr, 0, y, dinv,
                                                   Nn, 64, 0, flags);
  gather_kernel<<<gblocks, 256, 0, stream>>>(y, csr, rowptr, dinv, bg1,
                                             h3, 0, 0, Nn,
                                             nullptr, nullptr, nullptr, flags);

  gemm_tiled<2, 1, 0><<<tblocks, 256, 0, stream>>>(h3, pG2, nullptr, nullptr, 0, y, dinv,
                                                   Nn, 64, 0, flags);
  gather_kernel<<<gblocks, 256, 0, stream>>>(y, csr, rowptr, dinv, bg2,
                                             d_out, (size_t)EL, 1, Nn,
                                             ssrc, sdst, Wp, flags);

  edge_head_kernel<<<(EL + 255) / 256, 256, 0, stream>>>(d_out, eli, ea, ssrc, sdst,
                                                         Wp, bp, EL, flags);
}